// Round 4
// baseline (276.075 us; speedup 1.0000x reference)
//
#include <hip/hip_runtime.h>
#include <hip/hip_bf16.h>
#include <math.h>

#define NN 40000
#define NE 640000

typedef __attribute__((ext_vector_type(8))) short short8;
typedef __attribute__((ext_vector_type(8))) unsigned short u16x8;
typedef __attribute__((ext_vector_type(4))) float f32x4;
typedef __attribute__((ext_vector_type(2))) float f32v2;
typedef _Float16 h16x2 __attribute__((ext_vector_type(2)));

#define WBLOCKS 547   // weight-prep blocks
#define GBLOCKS 625   // GEMM row blocks (NN/64)
#define NCO 157       // coarse buckets (dst>>8)
#define P1B 160       // scatter blocks
#define EPB 4000      // edges per scatter block (NE/P1B)
#define BCAP 5120     // padded capacity per coarse bucket (16 sigma margin)

#if __has_builtin(__builtin_amdgcn_cvt_pk_f32_fp8) && __has_builtin(__builtin_amdgcn_cvt_pk_fp8_f32)
#define HAS_FP8CVT 1
#else
#define HAS_FP8CVT 0
#endif

__device__ __forceinline__ float fast_exp2(float x) {
#if __has_builtin(__builtin_amdgcn_exp2f)
    return __builtin_amdgcn_exp2f(x);
#else
    return exp2f(x);
#endif
}

// tanh-gelu, mathematically identical to 0.5x(1+tanh(u)) via tanh(u)=1-2/(1+e^{2u})
__device__ __forceinline__ float gelu_tanh(float x) {
    float x3 = x * x * x;
    float u = 0.7978845608028654f * (x + 0.044715f * x3);
    float t = 1.0f - 2.0f / (1.0f + fast_exp2(2.885390081777927f * u));
    return 0.5f * x * (1.0f + t);
}

__device__ __forceinline__ unsigned short f2bf(float v) {
    __hip_bfloat16 h = __float2bfloat16(v);
    return *reinterpret_cast<unsigned short*>(&h);
}

__device__ __forceinline__ unsigned short f2h(float v) {
    union { _Float16 h; unsigned short u; } c;
    c.h = (_Float16)v;
    return c.u;
}

__device__ __forceinline__ float bf2f(unsigned short u) {
    union { unsigned int i; float f; } c;
    c.i = ((unsigned int)u) << 16;
    return c.f;
}

// ---------------- fp8 e4m3 pack/unpack --------------------------------------
#if HAS_FP8CVT
__device__ __forceinline__ unsigned int f32x4_to_fp8(float a, float b, float c, float d) {
    int r = 0;
    r = __builtin_amdgcn_cvt_pk_fp8_f32(a, b, r, false);
    r = __builtin_amdgcn_cvt_pk_fp8_f32(c, d, r, true);
    return (unsigned int)r;
}
__device__ __forceinline__ void fp8x4_to_f32(unsigned int w, float* o) {
    f32v2 lo = __builtin_amdgcn_cvt_pk_f32_fp8((int)w, false);
    f32v2 hi = __builtin_amdgcn_cvt_pk_f32_fp8((int)w, true);
    o[0] = lo[0]; o[1] = lo[1]; o[2] = hi[0]; o[3] = hi[1];
}
#else
__device__ __forceinline__ unsigned char f2fp8_sw(float x) {
    union { float f; unsigned u; } c; c.f = x;
    unsigned sgn = (c.u >> 31) << 7;
    c.u &= 0x7fffffffu;
    if (!(c.f < 464.f)) return (unsigned char)(sgn | 0x7e);
    if (c.f < 0.0009765625f) return (unsigned char)sgn;
    if (c.f < 0.015625f) {
        int q = (int)rintf(c.f * 512.f);
        if (q > 7) return (unsigned char)(sgn | 0x08);
        return (unsigned char)(sgn | q);
    }
    unsigned u = c.u;
    unsigned lsb = (u >> 20) & 1;
    u += 0x7ffffu + lsb;
    int e8 = (int)(u >> 23) - 127 + 7;
    if (e8 > 15) return (unsigned char)(sgn | 0x7e);
    unsigned m = (u >> 20) & 7;
    return (unsigned char)(sgn | (e8 << 3) | m);
}
__device__ __forceinline__ float fp8_to_f32_sw(unsigned char b) {
    int e = (b >> 3) & 15, m = b & 7;
    float v = (e == 0) ? ldexpf((float)m, -9) : ldexpf(8.0f + (float)m, e - 10);
    return (b & 0x80) ? -v : v;
}
__device__ __forceinline__ unsigned int f32x4_to_fp8(float a, float b, float c, float d) {
    return (unsigned int)f2fp8_sw(a) | ((unsigned int)f2fp8_sw(b) << 8) |
           ((unsigned int)f2fp8_sw(c) << 16) | ((unsigned int)f2fp8_sw(d) << 24);
}
__device__ __forceinline__ void fp8x4_to_f32(unsigned int w, float* o) {
    o[0] = fp8_to_f32_sw((unsigned char)(w & 0xff));
    o[1] = fp8_to_f32_sw((unsigned char)((w >> 8) & 0xff));
    o[2] = fp8_to_f32_sw((unsigned char)((w >> 16) & 0xff));
    o[3] = fp8_to_f32_sw((unsigned char)((w >> 24) & 0xff));
}
#endif

union kv8 { u16x8 u; h16x2 p[4]; _Float16 h[8]; };
union frag8 { short8 s; unsigned short u[8]; u16x8 v; };

// ---- merged: coarse scatter w/ atomic range reservation (blocks 0..P1B-1) ----
// ---- + weight prep (blocks P1B..P1B+WBLOCKS-1) --------------------------------
__global__ __launch_bounds__(256) void prep_kernel(
    const float* __restrict__ Wq, const float* __restrict__ bq,
    const float* __restrict__ Wk, const float* __restrict__ bk,
    const float* __restrict__ a_rel,
    const float* __restrict__ Wv, const float* __restrict__ bv,
    const float* __restrict__ m_rel,
    const float* __restrict__ p_rel,
    const float* __restrict__ aW, const float* __restrict__ fcW,
    unsigned short* __restrict__ BfT, float* __restrict__ biasf,
    unsigned short* __restrict__ aWT, unsigned short* __restrict__ fcWT,
    const int* __restrict__ eidx, int* __restrict__ gcur, int* __restrict__ ebuk)
{
    if (blockIdx.x < P1B) {
        // coarse bucketing: per-block LDS hist -> reserve global ranges -> scatter.
        __shared__ int cnt[NCO];
        __shared__ int cur[NCO];
        int b = blockIdx.x;
        int t = threadIdx.x;
        if (t < NCO) cnt[t] = 0;
        __syncthreads();
        int bs = b * EPB;
        for (int e = bs + t; e < bs + EPB; e += 256)
            atomicAdd(&cnt[eidx[NE + e] >> 8], 1);
        __syncthreads();
        if (t < NCO) cur[t] = atomicAdd(&gcur[t], cnt[t]);
        __syncthreads();
        for (int e = bs + t; e < bs + EPB; e += 256) {
            int s = eidx[e];
            int d = eidx[NE + e];
            int cb = d >> 8;
            int pos = atomicAdd(&cur[cb], 1);
            ebuk[cb * BCAP + pos] = ((d & 255) << 16) | s;
        }
        return;
    }
    int idx = (blockIdx.x - P1B) * 256 + threadIdx.x;
    if (idx < 2 * 129 * 384) {
        int l = idx / (129 * 384);
        int j = idx - l * (129 * 384);
        int r = j / 384;
        int col = j - r * 384;
        const float* Wq_l = Wq + l * 16384;
        const float* Wk_l = Wk + l * 16384;
        const float* Wv_l = Wv + l * 16384;
        const float* ar_l = a_rel + l * 2048;
        const float* mr_l = m_rel + l * 2048;
        float val;
        if (col < 128) {
            val = (r < 128) ? Wq_l[r * 128 + col] : bq[l * 128 + col];
        } else if (col < 256) {
            int cc = col - 128; int h = cc >> 4; int eo = cc & 15;
            float scale = p_rel[l * 8 + h] * 0.25f * 1.4426950408889634f;
            float s = 0.f;
            #pragma unroll
            for (int d = 0; d < 16; ++d) {
                float w = (r < 128) ? Wk_l[r * 128 + h * 16 + d] : bk[l * 128 + h * 16 + d];
                s += w * ar_l[h * 256 + d * 16 + eo];
            }
            val = s * scale;
        } else {
            int cc = col - 256; int h = cc >> 4; int eo = cc & 15;
            float s = 0.f;
            #pragma unroll
            for (int d = 0; d < 16; ++d) {
                float w = (r < 128) ? Wv_l[r * 128 + h * 16 + d] : bv[l * 128 + h * 16 + d];
                s += w * mr_l[h * 256 + d * 16 + eo];
            }
            val = s;
        }
        if (r < 128) BfT[(size_t)l * 49152 + (size_t)col * 128 + r] = f2bf(val);
        else         biasf[l * 384 + col] = val;
    } else if (idx < 2 * 129 * 384 + 2 * 16384) {
        int i = idx - 2 * 129 * 384;
        int l = i >> 14; int j = i & 16383;
        int r = j >> 7, c = j & 127;
        aWT[(size_t)l * 16384 + (size_t)c * 128 + r] = f2bf(aW[(size_t)l * 16384 + r * 128 + c]);
    } else {
        int i = idx - (2 * 129 * 384 + 2 * 16384);
        int c = i >> 7, r = i & 127;
        fcWT[(size_t)c * 128 + r] = f2bf(fcW[(size_t)r * 64 + c]);
    }
}

// ---- qkv0 GEMM (blocks 0..624) + CSR pass 3 (blocks 625..781) -------------------
// qb rows: f16 [NN][128].  kvb rows: [k fp8 (128 B) | v fp8 (128 B)], 256 B.
__global__ __launch_bounds__(256) void qkv0_p3_kernel(
    const float* __restrict__ Af, const unsigned short* __restrict__ BT,
    const float* __restrict__ bias,
    unsigned short* __restrict__ qb, unsigned char* __restrict__ kvb,
    const int* __restrict__ gcnt, const int* __restrict__ ebuk,
    int* __restrict__ podeg, int* __restrict__ srcSorted)
{
    if (blockIdx.x >= GBLOCKS) {
        // pass 3: fine grouping within one coarse bucket, LDS only
        __shared__ int hist[256], loffs[256], cur[256];
        int c = blockIdx.x - GBLOCKS;
        int t = threadIdx.x;
        int base = c * BCAP;
        int end = base + gcnt[c];
        hist[t] = 0;
        __syncthreads();
        for (int i = base + t; i < end; i += 256)
            atomicAdd(&hist[ebuk[i] >> 16], 1);
        __syncthreads();
        int v = hist[t];
        loffs[t] = v;
        __syncthreads();
        #pragma unroll
        for (int off = 1; off < 256; off <<= 1) {
            int u = (t >= off) ? loffs[t - off] : 0;
            __syncthreads();
            loffs[t] += u;
            __syncthreads();
        }
        int excl = loffs[t] - v;
        int n = c * 256 + t;
        if (n < NN) podeg[n] = (base + excl) | (v << 20);   // offs in low 20 bits, deg high
        cur[t] = excl;
        __syncthreads();
        for (int i = base + t; i < end; i += 256) {
            int p = ebuk[i];
            int pos = atomicAdd(&cur[p >> 16], 1);
            srcSorted[base + pos] = p & 0xffff;
        }
        return;
    }
    __shared__ unsigned short Bs[64][136];
    int t = threadIdx.x;
    int row0 = blockIdx.x * 64;
    int w = t >> 6;
    int lr = t & 15;
    int quad = (t & 63) >> 4;
    int row = row0 + w * 16 + lr;

    frag8 af[4];
    {
        const float* ap = Af + (size_t)row * 128 + quad * 8;
        #pragma unroll
        for (int kc = 0; kc < 4; ++kc) {
            float4 a0 = *(const float4*)(ap + kc * 32);
            float4 a1 = *(const float4*)(ap + kc * 32 + 4);
            af[kc].u[0] = f2bf(a0.x); af[kc].u[1] = f2bf(a0.y);
            af[kc].u[2] = f2bf(a0.z); af[kc].u[3] = f2bf(a0.w);
            af[kc].u[4] = f2bf(a1.x); af[kc].u[5] = f2bf(a1.y);
            af[kc].u[6] = f2bf(a1.z); af[kc].u[7] = f2bf(a1.w);
        }
    }

    #pragma unroll
    for (int ct = 0; ct < 6; ++ct) {
        if (ct) __syncthreads();
        #pragma unroll
        for (int i = 0; i < 4; ++i) {
            int idx = t + i * 256;
            int r = idx >> 4;
            int c8 = (idx & 15) * 8;
            *(u16x8*)(&Bs[r][c8]) = *(const u16x8*)(BT + (size_t)(ct * 64 + r) * 128 + c8);
        }
        __syncthreads();
        f32x4 acc[4] = {{0.f,0.f,0.f,0.f},{0.f,0.f,0.f,0.f},
                        {0.f,0.f,0.f,0.f},{0.f,0.f,0.f,0.f}};
        #pragma unroll
        for (int kc = 0; kc < 4; ++kc) {
            #pragma unroll
            for (int n4 = 0; n4 < 4; ++n4) {
                short8 bfr = *(const short8*)(&Bs[n4 * 16 + lr][kc * 32 + quad * 8]);
                acc[n4] = __builtin_amdgcn_mfma_f32_16x16x32_bf16(bfr, af[kc].s, acc[n4], 0, 0, 0);
            }
        }
        if (ct < 2) {
            unsigned short* dst = qb + (size_t)row * 128 + ct * 64;
            #pragma unroll
            for (int n4 = 0; n4 < 4; ++n4) {
                int colb = n4 * 16 + quad * 4;
                float4 bv = *(const float4*)(bias + ct * 64 + colb);
                ushort4 o;
                o.x = f2h(acc[n4][0] + bv.x);
                o.y = f2h(acc[n4][1] + bv.y);
                o.z = f2h(acc[n4][2] + bv.z);
                o.w = f2h(acc[n4][3] + bv.w);
                *(ushort4*)(dst + colb) = o;
            }
        } else {
            unsigned char* dst = kvb + (size_t)row * 256 + (ct - 2) * 64;
            #pragma unroll
            for (int n4 = 0; n4 < 4; ++n4) {
                int colb = n4 * 16 + quad * 4;
                float4 bv = *(const float4*)(bias + ct * 64 + colb);
                *(unsigned int*)(dst + colb) = f32x4_to_fp8(
                    acc[n4][0] + bv.x, acc[n4][1] + bv.y,
                    acc[n4][2] + bv.z, acc[n4][3] + bv.w);
            }
        }
    }
}

// Merged: per-block aggregation of its own 64 rows -> LDS -> out-GEMM -> next GEMM.
// Phase A: 4 waves x 16 nodes each; 64 lanes = 8 edge-slots x 8 heads per node.
// Phase B: gelu(agg)@aWT + skip -> h; Phase C: h @ W2T (QKV-1 or fc).
template <int HPFMT, int P2>
__global__ __launch_bounds__(256) void merged_kernel(
    const unsigned short* __restrict__ qb, const unsigned char* __restrict__ kvb,
    const int* __restrict__ podeg, const int* __restrict__ srcSorted,
    const unsigned short* __restrict__ aWT, const float* __restrict__ ab,
    const float* __restrict__ skip_p,
    const float* __restrict__ HprevF, const unsigned short* __restrict__ HprevB,
    unsigned short* __restrict__ hb_out,
    const unsigned short* __restrict__ W2T, const float* __restrict__ bias2,
    unsigned short* __restrict__ qb_out, unsigned char* __restrict__ kvb_out,
    float* __restrict__ outF)
{
    __shared__ unsigned short As[64][136];
    __shared__ unsigned short Bs[64][136];
    int t = threadIdx.x;
    int row0 = blockIdx.x * 64;
    int w = t >> 6;
    int lane = t & 63;
    int es = lane >> 3;
    int h = lane & 7;

    // ---------- phase A: aggregate this block's 64 rows into As ----------
    for (int it = 0; it < 16; ++it) {
        int n = row0 + w * 16 + it;
        float qf[16];
        {
            kv8 a, b;
            a.u = *(const u16x8*)(qb + (size_t)n * 128 + h * 16);
            b.u = *(const u16x8*)(qb + (size_t)n * 128 + h * 16 + 8);
            #pragma unroll
            for (int j = 0; j < 8; ++j) { qf[j] = (float)a.h[j]; qf[8 + j] = (float)b.h[j]; }
        }
        float acc[16];
        #pragma unroll
        for (int j = 0; j < 16; ++j) acc[j] = 0.f;
        float den = 0.f;

        int pd = podeg[n];
        int start = pd & 0xFFFFF;
        int d = ((unsigned)pd) >> 20;
        if (d > 0) {
            int ng = (d + 7) >> 3;
            int lastIdx = start + d - 1;

            int4 kA, vA, kB, vB;
            {
                int i0 = start + es; if (i0 > lastIdx) i0 = lastIdx;
                const unsigned char* p = kvb + (size_t)srcSorted[i0] * 256 + h * 16;
                kA = *(const int4*)p;
                vA = *(const int4*)(p + 128);
            }
            kB = kA; vB = vA;
            if (ng > 1) {
                int i1 = start + 8 + es; if (i1 > lastIdx) i1 = lastIdx;
                const unsigned char* p = kvb + (size_t)srcSorted[i1] * 256 + h * 16;
                kB = *(const int4*)p;
                vB = *(const int4*)(p + 128);
            }

            for (int g = 0; g < ng; ++g) {
                int4 kC = kA, vC = vA;
                if (g + 2 < ng) {
                    int ni = start + (g + 2) * 8 + es; if (ni > lastIdx) ni = lastIdx;
                    const unsigned char* p = kvb + (size_t)srcSorted[ni] * 256 + h * 16;
                    kC = *(const int4*)p;
                    vC = *(const int4*)(p + 128);
                }
                float pdot = 0.f;
                {
                    float kf[16];
                    fp8x4_to_f32((unsigned int)kA.x, kf);
                    fp8x4_to_f32((unsigned int)kA.y, kf + 4);
                    fp8x4_to_f32((unsigned int)kA.z, kf + 8);
                    fp8x4_to_f32((unsigned int)kA.w, kf + 12);
                    #pragma unroll
                    for (int j = 0; j < 16; ++j) pdot = fmaf(kf[j], qf[j], pdot);
                }
                float ev = (g * 8 + es < d) ? fast_exp2(pdot) : 0.f;
                den += ev;
                {
                    float vf[16];
                    fp8x4_to_f32((unsigned int)vA.x, vf);
                    fp8x4_to_f32((unsigned int)vA.y, vf + 4);
                    fp8x4_to_f32((unsigned int)vA.z, vf + 8);
                    fp8x4_to_f32((unsigned int)vA.w, vf + 12);
                    #pragma unroll
                    for (int j = 0; j < 16; ++j) acc[j] = fmaf(vf[j], ev, acc[j]);
                }
                kA = kB; vA = vB;
                kB = kC; vB = vC;
            }
        }
        #pragma unroll
        for (int m = 8; m < 64; m <<= 1) {
            den += __shfl_xor(den, m, 64);
            #pragma unroll
            for (int j = 0; j < 16; ++j) acc[j] += __shfl_xor(acc[j], m, 64);
        }
        if (es == 0) {
            float wd = 1.f / (den + 1e-16f);
            u16x8 o0, o1;
            #pragma unroll
            for (int j = 0; j < 8; ++j) {
                o0[j] = f2bf(acc[j] * wd);
                o1[j] = f2bf(acc[j + 8] * wd);
            }
            *(u16x8*)(&As[w * 16 + it][h * 16]) = o0;
            *(u16x8*)(&As[w * 16 + it][h * 16 + 8]) = o1;
        }
    }
    __syncthreads();

    // ---------- phase B: gelu(agg) @ aWT + skip -> h ----------
    int lr = t & 15;
    int quad = (t & 63) >> 4;
    int row = row0 + w * 16 + lr;

    frag8 agf[4];
    #pragma unroll
    for (int kc = 0; kc < 4; ++kc) {
        u16x8 u = *(const u16x8*)(&As[w * 16 + lr][kc * 32 + quad * 8]);
        #pragma unroll
        for (int j = 0; j < 8; ++j) agf[kc].u[j] = f2bf(gelu_tanh(bf2f(u[j])));
    }

    float sv = skip_p[0];
    float beta = 1.f / (1.f + expf(-sv));
    float omb = 1.f - beta;

    f32x4 hacc[2][4];
    #pragma unroll
    for (int ct = 0; ct < 2; ++ct) {
        __syncthreads();   // ct=0: protect As (agf reads done); ct=1: protect Bs
        #pragma unroll
        for (int i = 0; i < 4; ++i) {
            int idx = t + i * 256;
            int r = idx >> 4;
            int c8 = (idx & 15) * 8;
            *(u16x8*)(&Bs[r][c8]) = *(const u16x8*)(aWT + (size_t)(ct * 64 + r) * 128 + c8);
        }
        __syncthreads();
        #pragma unroll
        for (int n4 = 0; n4 < 4; ++n4) hacc[ct][n4] = (f32x4){0.f,0.f,0.f,0.f};
        #pragma unroll
        for (int kc = 0; kc < 4; ++kc) {
            #pragma unroll
            for (int n4 = 0; n4 < 4; ++n4) {
                short8 bfr = *(const short8*)(&Bs[n4 * 16 + lr][kc * 32 + quad * 8]);
                hacc[ct][n4] = __builtin_amdgcn_mfma_f32_16x16x32_bf16(bfr, agf[kc].s, hacc[ct][n4], 0, 0, 0);
            }
        }
    }
    __syncthreads();   // all MFMA Bs-reads and As agf-reads complete before h overwrite

    #pragma unroll
    for (int ct = 0; ct < 2; ++ct) {
        #pragma unroll
        for (int n4 = 0; n4 < 4; ++n4) {
            int colb = ct * 64 + n4 * 16 + quad * 4;
            float4 bv = *(const float4*)(ab + colb);
            float hp[4];
            if (HPFMT == 0) {
                float4 h4 = *(const float4*)(HprevF + (size_t)row * 128 + colb);
                hp[0] = h4.x; hp[1] = h4.y; hp[2] = h4.z; hp[3] = h4.w;
            } else {
                ushort4 h4 = *(const ushort4*)(HprevB + (size_t)row * 128 + colb);
                hp[0] = bf2f(h4.x); hp[1] = bf2f(h4.y); hp[2] = bf2f(h4.z); hp[3] = bf2f(h4.w);
            }
            ushort4 o;
            o.x = f2bf(fmaxf(beta * (hacc[ct][n4][0] + bv.x) + omb * hp[0], 0.f));
            o.y = f2bf(fmaxf(beta * (hacc[ct][n4][1] + bv.y) + omb * hp[1], 0.f));
            o.z = f2bf(fmaxf(beta * (hacc[ct][n4][2] + bv.z) + omb * hp[2], 0.f));
            o.w = f2bf(fmaxf(beta * (hacc[ct][n4][3] + bv.w) + omb * hp[3], 0.f));
            *(ushort4*)(&As[w * 16 + lr][colb]) = o;
            if (P2 == 0) *(ushort4*)(hb_out + (size_t)row * 128 + colb) = o;
        }
    }
    __syncthreads();

    // ---------- phase C: h @ W2T ----------
    if (P2 == 0) {
        #pragma unroll
        for (int ct = 0; ct < 6; ++ct) {
            if (ct) __syncthreads();
            #pragma unroll
            for (int i = 0; i < 4; ++i) {
                int idx = t + i * 256;
                int r = idx >> 4;
                int c8 = (idx & 15) * 8;
                *(u16x8*)(&Bs[r][c8]) = *(const u16x8*)(W2T + (size_t)(ct * 64 + r) * 128 + c8);
            }
            __syncthreads();
            f32x4 acc[4] = {{0.f,0.f,0.f,0.f},{0.f,0.f,0.f,0.f},
                            {0.f,0.f,0.f,0.f},{0.f,0.f,0.f,0.f}};
            #pragma unroll
            for (int kc = 0; kc < 4; ++kc) {
                short8 afr = *(const short8*)(&As[w * 16 + lr][kc * 32 + quad * 8]);
                #pragma unroll
                for (int n4 = 0; n4 < 4; ++n4) {
                    short8 bfr = *(const short8*)(&Bs[n4 * 16 + lr][kc * 32 + quad * 8]);
                    acc[n4] = __builtin_amdgcn_mfma_f32_16x16x32_bf16(bfr, afr, acc[n4], 0, 0, 0);
                }
            }
            if (ct < 2) {
                unsigned short* dst = qb_out + (size_t)row * 128 + ct * 64;
                #pragma unroll
                for (int n4 = 0; n4 < 4; ++n4) {
                    int colb = n4 * 16 + quad * 4;
                    float4 bv = *(const float4*)(bias2 + ct * 64 + colb);
                    ushort4 o;
                    o.x = f2h(acc[n4][0] + bv.x);
                    o.y = f2h(acc[n4][1] + bv.y);
                    o.z = f2h(acc[n4][2] + bv.z);
                    o.w = f2h(acc[n4][3] + bv.w);
                    *(ushort4*)(dst + colb) = o;
                }
            } else {
                unsigned char* dst = kvb_out + (size_t)row * 256 + (ct - 2) * 64;
                #pragma unroll
                for (int n4 = 0; n4 < 4; ++n4) {
                    int colb = n4 * 16 + quad * 4;
                    float4 bv = *(const float4*)(bias2 + ct * 64 + colb);
                    *(unsigned int*)(dst + colb) = f32x4_to_fp8(
                        acc[n4][0] + bv.x, acc[n4][1] + bv.y,
                        acc[n4][2] + bv.z, acc[n4][3] + bv.w);
                }
            }
        }
    } else {
        #pragma unroll
        for (int i = 0; i < 4; ++i) {
            int idx = t + i * 256;
            int r = idx >> 4;
            int c8 = (idx & 15) * 8;
            *(u16x8*)(&Bs[r][c8]) = *(const u16x8*)(W2T + (size_t)r * 128 + c8);
        }
        __syncthreads();
        f32x4 acc[4] = {{0.f,0.f,0.f,0.f},{0.f,0.f,0.f,0.f},
                        {0.f,0.f,0.f,0.f},{0.f,0.f,0.f,0.f}};
        #pragma unroll
        for (int kc = 0; kc < 4; ++kc) {
            short8 afr = *(const short8*)(&As[w * 16 + lr][kc * 32 + quad * 8]);
            #pragma unroll
            for (int n4 = 0; n4 < 4; ++n4) {
                short8 bfr = *(const short8*)(&Bs[n4 * 16 + lr][kc * 32 + quad * 8]);
                acc[n4] = __builtin_amdgcn_mfma_f32_16x16x32_bf16(bfr, afr, acc[n4], 0, 0, 0);
            }
        }
        #pragma unroll
        for (int n4 = 0; n4 < 4; ++n4) {
            int colb = n4 * 16 + quad * 4;
            float4 bv = *(const float4*)(bias2 + colb);
            float4 o;
            o.x = acc[n4][0] + bv.x;
            o.y = acc[n4][1] + bv.y;
            o.z = acc[n4][2] + bv.z;
            o.w = acc[n4][3] + bv.w;
            *(float4*)(outF + (size_t)row * 64 + colb) = o;
        }
    }
}

extern "C" void kernel_launch(void* const* d_in, const int* in_sizes, int n_in,
                              void* d_out, int out_size, void* d_ws, size_t ws_size,
                              hipStream_t stream) {
    const float* x     = (const float*)d_in[0];
    const int*   eidx  = (const int*)d_in[1];
    const float* Wk    = (const float*)d_in[2];
    const float* bk    = (const float*)d_in[3];
    const float* Wq    = (const float*)d_in[4];
    const float* bq    = (const float*)d_in[5];
    const float* Wv    = (const float*)d_in[6];
    const float* bv    = (const float*)d_in[7];
    const float* a_rel = (const float*)d_in[8];
    const float* m_rel = (const float*)d_in[9];
    const float* p_rel = (const float*)d_in[10];
    const float* skip  = (const float*)d_in[11];
    const float* aW    = (const float*)d_in[12];
    const float* ab    = (const float*)d_in[13];
    const float* fcW   = (const float*)d_in[14];
    const float* fcb   = (const float*)d_in[15];
    float* out = (float*)d_out;

    float* biasf = (float*)d_ws;                              // 2*384
    unsigned short* hb   = (unsigned short*)(biasf + 768);    // NN*128 bf16
    unsigned short* qb0  = hb + (size_t)NN * 128;             // NN*128 f16
    unsigned char*  kvb0 = (unsigned char*)(qb0 + (size_t)NN * 128); // NN*256 B fp8
    unsigned short* qb1  = (unsigned short*)(kvb0 + (size_t)NN * 256); // NN*128 f16
    unsigned char*  kvb1 = (unsigned char*)(qb1 + (size_t)NN * 128);   // NN*256 B fp8
    unsigned short* BfT  = (unsigned short*)(kvb1 + (size_t)NN * 256); // 2*384*128
    unsigned short* aWT  = BfT + 2 * 384 * 128;               // 2*128*128
    unsigned short* fcWT = aWT + 2 * 128 * 128;               // 64*128
    int* podeg     = (int*)(fcWT + 64 * 128);                 // NN (offs | deg<<20)
    int* gcur      = podeg + NN;                              // NCO (pad 160)
    int* ebuk      = gcur + 160;                              // NCO*BCAP
    int* srcSorted = ebuk + NCO * BCAP;                       // NCO*BCAP

    // zero the coarse-bucket cursors (captured as a graph memset node)
    hipMemsetAsync(gcur, 0, NCO * sizeof(int), stream);

    // weights + coarse scatter (one dispatch, disjoint block ranges)
    prep_kernel<<<P1B + WBLOCKS, 256, 0, stream>>>(
        Wq, bq, Wk, bk, a_rel, Wv, bv, m_rel, p_rel, aW, fcW,
        BfT, biasf, aWT, fcWT, eidx, gcur, ebuk);

    // layer-0 QKV GEMM + CSR pass 3 (co-scheduled)
    qkv0_p3_kernel<<<GBLOCKS + NCO, 256, 0, stream>>>(
        x, BfT, biasf, qb0, kvb0, gcur, ebuk, podeg, srcSorted);

    // agg(L0) + out-GEMM(L0) -> h0 -> QKV(L1)   [writes qb1/kvb1: double-buffered]
    merged_kernel<0, 0><<<GBLOCKS, 256, 0, stream>>>(
        qb0, kvb0, podeg, srcSorted, aWT, ab, skip, x, nullptr, hb,
        BfT + 49152, biasf + 384, qb1, kvb1, nullptr);

    // agg(L1) + out-GEMM(L1) -> h1 -> fc -> out
    merged_kernel<1, 2><<<GBLOCKS, 256, 0, stream>>>(
        qb1, kvb1, podeg, srcSorted, aWT + 16384, ab + 128, skip + 1, nullptr, hb, nullptr,
        fcWT, fcb, nullptr, nullptr, out);
}

// Round 5
// 245.375 us; speedup vs baseline: 1.1251x; 1.1251x over previous
//
#include <hip/hip_runtime.h>
#include <hip/hip_bf16.h>
#include <math.h>

#define NN 40000
#define NE 640000

typedef __attribute__((ext_vector_type(8))) short short8;
typedef __attribute__((ext_vector_type(8))) unsigned short u16x8;
typedef __attribute__((ext_vector_type(4))) float f32x4;
typedef __attribute__((ext_vector_type(2))) float f32v2;
typedef _Float16 h16x2 __attribute__((ext_vector_type(2)));

#define WBLOCKS 547   // weight-prep blocks
#define GBLOCKS 625   // GEMM row blocks (NN/64)
#define NCO 157       // coarse buckets (dst>>8)
#define P1B 160       // scatter blocks
#define EPB 4000      // edges per scatter block (NE/P1B)
#define BCAP 5120     // padded capacity per coarse bucket (16 sigma margin)

#if __has_builtin(__builtin_amdgcn_cvt_pk_f32_fp8) && __has_builtin(__builtin_amdgcn_cvt_pk_fp8_f32)
#define HAS_FP8CVT 1
#else
#define HAS_FP8CVT 0
#endif

__device__ __forceinline__ float fast_exp2(float x) {
#if __has_builtin(__builtin_amdgcn_exp2f)
    return __builtin_amdgcn_exp2f(x);
#else
    return exp2f(x);
#endif
}

// tanh-gelu, mathematically identical to 0.5x(1+tanh(u)) via tanh(u)=1-2/(1+e^{2u})
__device__ __forceinline__ float gelu_tanh(float x) {
    float x3 = x * x * x;
    float u = 0.7978845608028654f * (x + 0.044715f * x3);
    float t = 1.0f - 2.0f / (1.0f + fast_exp2(2.885390081777927f * u));
    return 0.5f * x * (1.0f + t);
}

__device__ __forceinline__ unsigned short f2bf(float v) {
    __hip_bfloat16 h = __float2bfloat16(v);
    return *reinterpret_cast<unsigned short*>(&h);
}

__device__ __forceinline__ unsigned short f2h(float v) {
    union { _Float16 h; unsigned short u; } c;
    c.h = (_Float16)v;
    return c.u;
}

__device__ __forceinline__ float bf2f(unsigned short u) {
    union { unsigned int i; float f; } c;
    c.i = ((unsigned int)u) << 16;
    return c.f;
}

// ---------------- fp8 e4m3 pack/unpack --------------------------------------
#if HAS_FP8CVT
__device__ __forceinline__ unsigned int f32x4_to_fp8(float a, float b, float c, float d) {
    int r = 0;
    r = __builtin_amdgcn_cvt_pk_fp8_f32(a, b, r, false);
    r = __builtin_amdgcn_cvt_pk_fp8_f32(c, d, r, true);
    return (unsigned int)r;
}
__device__ __forceinline__ void fp8x4_to_f32(unsigned int w, float* o) {
    f32v2 lo = __builtin_amdgcn_cvt_pk_f32_fp8((int)w, false);
    f32v2 hi = __builtin_amdgcn_cvt_pk_f32_fp8((int)w, true);
    o[0] = lo[0]; o[1] = lo[1]; o[2] = hi[0]; o[3] = hi[1];
}
#else
__device__ __forceinline__ unsigned char f2fp8_sw(float x) {
    union { float f; unsigned u; } c; c.f = x;
    unsigned sgn = (c.u >> 31) << 7;
    c.u &= 0x7fffffffu;
    if (!(c.f < 464.f)) return (unsigned char)(sgn | 0x7e);
    if (c.f < 0.0009765625f) return (unsigned char)sgn;
    if (c.f < 0.015625f) {
        int q = (int)rintf(c.f * 512.f);
        if (q > 7) return (unsigned char)(sgn | 0x08);
        return (unsigned char)(sgn | q);
    }
    unsigned u = c.u;
    unsigned lsb = (u >> 20) & 1;
    u += 0x7ffffu + lsb;
    int e8 = (int)(u >> 23) - 127 + 7;
    if (e8 > 15) return (unsigned char)(sgn | 0x7e);
    unsigned m = (u >> 20) & 7;
    return (unsigned char)(sgn | (e8 << 3) | m);
}
__device__ __forceinline__ float fp8_to_f32_sw(unsigned char b) {
    int e = (b >> 3) & 15, m = b & 7;
    float v = (e == 0) ? ldexpf((float)m, -9) : ldexpf(8.0f + (float)m, e - 10);
    return (b & 0x80) ? -v : v;
}
__device__ __forceinline__ unsigned int f32x4_to_fp8(float a, float b, float c, float d) {
    return (unsigned int)f2fp8_sw(a) | ((unsigned int)f2fp8_sw(b) << 8) |
           ((unsigned int)f2fp8_sw(c) << 16) | ((unsigned int)f2fp8_sw(d) << 24);
}
__device__ __forceinline__ void fp8x4_to_f32(unsigned int w, float* o) {
    o[0] = fp8_to_f32_sw((unsigned char)(w & 0xff));
    o[1] = fp8_to_f32_sw((unsigned char)((w >> 8) & 0xff));
    o[2] = fp8_to_f32_sw((unsigned char)((w >> 16) & 0xff));
    o[3] = fp8_to_f32_sw((unsigned char)((w >> 24) & 0xff));
}
#endif

union kv8 { u16x8 u; h16x2 p[4]; _Float16 h[8]; };
union frag8 { short8 s; unsigned short u[8]; u16x8 v; };

// ---- merged: coarse scatter w/ atomic range reservation (blocks 0..P1B-1) ----
// ---- + weight prep (blocks P1B..P1B+WBLOCKS-1) --------------------------------
__global__ __launch_bounds__(256) void prep_kernel(
    const float* __restrict__ Wq, const float* __restrict__ bq,
    const float* __restrict__ Wk, const float* __restrict__ bk,
    const float* __restrict__ a_rel,
    const float* __restrict__ Wv, const float* __restrict__ bv,
    const float* __restrict__ m_rel,
    const float* __restrict__ p_rel,
    const float* __restrict__ aW, const float* __restrict__ fcW,
    unsigned short* __restrict__ BfT, float* __restrict__ biasf,
    unsigned short* __restrict__ aWT, unsigned short* __restrict__ fcWT,
    const int* __restrict__ eidx, int* __restrict__ gcur, int* __restrict__ ebuk)
{
    if (blockIdx.x < P1B) {
        // coarse bucketing: per-block LDS hist -> reserve global ranges -> scatter.
        __shared__ int cnt[NCO];
        __shared__ int cur[NCO];
        int b = blockIdx.x;
        int t = threadIdx.x;
        if (t < NCO) cnt[t] = 0;
        __syncthreads();
        int bs = b * EPB;
        for (int e = bs + t; e < bs + EPB; e += 256)
            atomicAdd(&cnt[eidx[NE + e] >> 8], 1);
        __syncthreads();
        if (t < NCO) cur[t] = atomicAdd(&gcur[t], cnt[t]);
        __syncthreads();
        for (int e = bs + t; e < bs + EPB; e += 256) {
            int s = eidx[e];
            int d = eidx[NE + e];
            int cb = d >> 8;
            int pos = atomicAdd(&cur[cb], 1);
            ebuk[cb * BCAP + pos] = ((d & 255) << 16) | s;
        }
        return;
    }
    int idx = (blockIdx.x - P1B) * 256 + threadIdx.x;
    if (idx < 2 * 129 * 384) {
        int l = idx / (129 * 384);
        int j = idx - l * (129 * 384);
        int r = j / 384;
        int col = j - r * 384;
        const float* Wq_l = Wq + l * 16384;
        const float* Wk_l = Wk + l * 16384;
        const float* Wv_l = Wv + l * 16384;
        const float* ar_l = a_rel + l * 2048;
        const float* mr_l = m_rel + l * 2048;
        float val;
        if (col < 128) {
            val = (r < 128) ? Wq_l[r * 128 + col] : bq[l * 128 + col];
        } else if (col < 256) {
            int cc = col - 128; int h = cc >> 4; int eo = cc & 15;
            float scale = p_rel[l * 8 + h] * 0.25f * 1.4426950408889634f;
            float s = 0.f;
            #pragma unroll
            for (int d = 0; d < 16; ++d) {
                float w = (r < 128) ? Wk_l[r * 128 + h * 16 + d] : bk[l * 128 + h * 16 + d];
                s += w * ar_l[h * 256 + d * 16 + eo];
            }
            val = s * scale;
        } else {
            int cc = col - 256; int h = cc >> 4; int eo = cc & 15;
            float s = 0.f;
            #pragma unroll
            for (int d = 0; d < 16; ++d) {
                float w = (r < 128) ? Wv_l[r * 128 + h * 16 + d] : bv[l * 128 + h * 16 + d];
                s += w * mr_l[h * 256 + d * 16 + eo];
            }
            val = s;
        }
        if (r < 128) BfT[(size_t)l * 49152 + (size_t)col * 128 + r] = f2bf(val);
        else         biasf[l * 384 + col] = val;
    } else if (idx < 2 * 129 * 384 + 2 * 16384) {
        int i = idx - 2 * 129 * 384;
        int l = i >> 14; int j = i & 16383;
        int r = j >> 7, c = j & 127;
        aWT[(size_t)l * 16384 + (size_t)c * 128 + r] = f2bf(aW[(size_t)l * 16384 + r * 128 + c]);
    } else {
        int i = idx - (2 * 129 * 384 + 2 * 16384);
        int c = i >> 7, r = i & 127;
        fcWT[(size_t)c * 128 + r] = f2bf(fcW[(size_t)r * 64 + c]);
    }
}

// ---- qkv0 GEMM (blocks 0..624) + CSR pass 3 (blocks 625..781) -------------------
// qb rows: f16 [NN][128].
// kvb rows (256 B, per-head interleave): [h][ k fp8 x16 (16B) | v fp8 x16 (16B) ].
__global__ __launch_bounds__(256) void qkv0_p3_kernel(
    const float* __restrict__ Af, const unsigned short* __restrict__ BT,
    const float* __restrict__ bias,
    unsigned short* __restrict__ qb, unsigned char* __restrict__ kvb,
    const int* __restrict__ gcnt, const int* __restrict__ ebuk,
    int* __restrict__ podeg, int* __restrict__ srcSorted)
{
    if (blockIdx.x >= GBLOCKS) {
        // pass 3: fine grouping within one coarse bucket, LDS only
        __shared__ int hist[256], loffs[256], cur[256];
        int c = blockIdx.x - GBLOCKS;
        int t = threadIdx.x;
        int base = c * BCAP;
        int end = base + gcnt[c];
        hist[t] = 0;
        __syncthreads();
        for (int i = base + t; i < end; i += 256)
            atomicAdd(&hist[ebuk[i] >> 16], 1);
        __syncthreads();
        int v = hist[t];
        loffs[t] = v;
        __syncthreads();
        #pragma unroll
        for (int off = 1; off < 256; off <<= 1) {
            int u = (t >= off) ? loffs[t - off] : 0;
            __syncthreads();
            loffs[t] += u;
            __syncthreads();
        }
        int excl = loffs[t] - v;
        int n = c * 256 + t;
        if (n < NN) podeg[n] = (base + excl) | (v << 20);   // offs low 20 bits, deg high
        cur[t] = excl;
        __syncthreads();
        for (int i = base + t; i < end; i += 256) {
            int p = ebuk[i];
            int pos = atomicAdd(&cur[p >> 16], 1);
            srcSorted[base + pos] = p & 0xffff;
        }
        return;
    }
    __shared__ unsigned short Bs[64][136];
    int t = threadIdx.x;
    int row0 = blockIdx.x * 64;
    int w = t >> 6;
    int lr = t & 15;
    int quad = (t & 63) >> 4;
    int row = row0 + w * 16 + lr;

    frag8 af[4];
    {
        const float* ap = Af + (size_t)row * 128 + quad * 8;
        #pragma unroll
        for (int kc = 0; kc < 4; ++kc) {
            float4 a0 = *(const float4*)(ap + kc * 32);
            float4 a1 = *(const float4*)(ap + kc * 32 + 4);
            af[kc].u[0] = f2bf(a0.x); af[kc].u[1] = f2bf(a0.y);
            af[kc].u[2] = f2bf(a0.z); af[kc].u[3] = f2bf(a0.w);
            af[kc].u[4] = f2bf(a1.x); af[kc].u[5] = f2bf(a1.y);
            af[kc].u[6] = f2bf(a1.z); af[kc].u[7] = f2bf(a1.w);
        }
    }

    #pragma unroll
    for (int ct = 0; ct < 6; ++ct) {
        if (ct) __syncthreads();
        #pragma unroll
        for (int i = 0; i < 4; ++i) {
            int idx = t + i * 256;
            int r = idx >> 4;
            int c8 = (idx & 15) * 8;
            *(u16x8*)(&Bs[r][c8]) = *(const u16x8*)(BT + (size_t)(ct * 64 + r) * 128 + c8);
        }
        __syncthreads();
        f32x4 acc[4] = {{0.f,0.f,0.f,0.f},{0.f,0.f,0.f,0.f},
                        {0.f,0.f,0.f,0.f},{0.f,0.f,0.f,0.f}};
        #pragma unroll
        for (int kc = 0; kc < 4; ++kc) {
            #pragma unroll
            for (int n4 = 0; n4 < 4; ++n4) {
                short8 bfr = *(const short8*)(&Bs[n4 * 16 + lr][kc * 32 + quad * 8]);
                acc[n4] = __builtin_amdgcn_mfma_f32_16x16x32_bf16(bfr, af[kc].s, acc[n4], 0, 0, 0);
            }
        }
        if (ct < 2) {
            unsigned short* dst = qb + (size_t)row * 128 + ct * 64;
            #pragma unroll
            for (int n4 = 0; n4 < 4; ++n4) {
                int colb = n4 * 16 + quad * 4;
                float4 bv = *(const float4*)(bias + ct * 64 + colb);
                ushort4 o;
                o.x = f2h(acc[n4][0] + bv.x);
                o.y = f2h(acc[n4][1] + bv.y);
                o.z = f2h(acc[n4][2] + bv.z);
                o.w = f2h(acc[n4][3] + bv.w);
                *(ushort4*)(dst + colb) = o;
            }
        } else {
            // K (ct 2,3) / V (ct 4,5) with per-head interleave: head*32 + isV*16 + eo
            unsigned char* dstrow = kvb + (size_t)row * 256;
            int isV = (ct >= 4);
            int hbase = (ct - (isV ? 4 : 2)) * 4;
            #pragma unroll
            for (int n4 = 0; n4 < 4; ++n4) {
                float4 bv = *(const float4*)(bias + ct * 64 + n4 * 16 + quad * 4);
                int off = (hbase + n4) * 32 + isV * 16 + quad * 4;
                *(unsigned int*)(dstrow + off) = f32x4_to_fp8(
                    acc[n4][0] + bv.x, acc[n4][1] + bv.y,
                    acc[n4][2] + bv.z, acc[n4][3] + bv.w);
            }
        }
    }
}

// Fused: out-GEMM (gelu(agg)@aWT + skip -> h) then second GEMM from h (in LDS).
template <int HPFMT, int P2>
__global__ __launch_bounds__(256) void fused_kernel(
    const unsigned short* __restrict__ aggb,
    const unsigned short* __restrict__ aWT, const float* __restrict__ ab,
    const float* __restrict__ skip_p,
    const float* __restrict__ HprevF, const unsigned short* __restrict__ HprevB,
    unsigned short* __restrict__ hb_out,
    const unsigned short* __restrict__ W2T, const float* __restrict__ bias2,
    unsigned short* __restrict__ qb, unsigned char* __restrict__ kvb,
    float* __restrict__ outF)
{
    __shared__ unsigned short As[64][136];
    __shared__ unsigned short Bs[64][136];
    int t = threadIdx.x;
    int row0 = blockIdx.x * 64;
    int w = t >> 6;
    int lr = t & 15;
    int quad = (t & 63) >> 4;
    int row = row0 + w * 16 + lr;

    frag8 agf[4];
    {
        const unsigned short* ap = aggb + (size_t)row * 128 + quad * 8;
        #pragma unroll
        for (int kc = 0; kc < 4; ++kc) {
            u16x8 u = *(const u16x8*)(ap + kc * 32);
            #pragma unroll
            for (int j = 0; j < 8; ++j) agf[kc].u[j] = f2bf(gelu_tanh(bf2f(u[j])));
        }
    }

    float sv = skip_p[0];
    float beta = 1.f / (1.f + expf(-sv));
    float omb = 1.f - beta;

    f32x4 hacc[2][4];
    #pragma unroll
    for (int ct = 0; ct < 2; ++ct) {
        if (ct) __syncthreads();
        #pragma unroll
        for (int i = 0; i < 4; ++i) {
            int idx = t + i * 256;
            int r = idx >> 4;
            int c8 = (idx & 15) * 8;
            *(u16x8*)(&Bs[r][c8]) = *(const u16x8*)(aWT + (size_t)(ct * 64 + r) * 128 + c8);
        }
        __syncthreads();
        #pragma unroll
        for (int n4 = 0; n4 < 4; ++n4) hacc[ct][n4] = (f32x4){0.f,0.f,0.f,0.f};
        #pragma unroll
        for (int kc = 0; kc < 4; ++kc) {
            #pragma unroll
            for (int n4 = 0; n4 < 4; ++n4) {
                short8 bfr = *(const short8*)(&Bs[n4 * 16 + lr][kc * 32 + quad * 8]);
                hacc[ct][n4] = __builtin_amdgcn_mfma_f32_16x16x32_bf16(bfr, agf[kc].s, hacc[ct][n4], 0, 0, 0);
            }
        }
    }

    #pragma unroll
    for (int ct = 0; ct < 2; ++ct) {
        #pragma unroll
        for (int n4 = 0; n4 < 4; ++n4) {
            int colb = ct * 64 + n4 * 16 + quad * 4;
            float4 bv = *(const float4*)(ab + colb);
            float hp[4];
            if (HPFMT == 0) {
                float4 h4 = *(const float4*)(HprevF + (size_t)row * 128 + colb);
                hp[0] = h4.x; hp[1] = h4.y; hp[2] = h4.z; hp[3] = h4.w;
            } else {
                ushort4 h4 = *(const ushort4*)(HprevB + (size_t)row * 128 + colb);
                hp[0] = bf2f(h4.x); hp[1] = bf2f(h4.y); hp[2] = bf2f(h4.z); hp[3] = bf2f(h4.w);
            }
            ushort4 o;
            o.x = f2bf(fmaxf(beta * (hacc[ct][n4][0] + bv.x) + omb * hp[0], 0.f));
            o.y = f2bf(fmaxf(beta * (hacc[ct][n4][1] + bv.y) + omb * hp[1], 0.f));
            o.z = f2bf(fmaxf(beta * (hacc[ct][n4][2] + bv.z) + omb * hp[2], 0.f));
            o.w = f2bf(fmaxf(beta * (hacc[ct][n4][3] + bv.w) + omb * hp[3], 0.f));
            *(ushort4*)(&As[w * 16 + lr][colb]) = o;
            if (P2 == 0) *(ushort4*)(hb_out + (size_t)row * 128 + colb) = o;
        }
    }
    __syncthreads();

    if (P2 == 0) {
        #pragma unroll
        for (int ct = 0; ct < 6; ++ct) {
            if (ct) __syncthreads();
            #pragma unroll
            for (int i = 0; i < 4; ++i) {
                int idx = t + i * 256;
                int r = idx >> 4;
                int c8 = (idx & 15) * 8;
                *(u16x8*)(&Bs[r][c8]) = *(const u16x8*)(W2T + (size_t)(ct * 64 + r) * 128 + c8);
            }
            __syncthreads();
            f32x4 acc[4] = {{0.f,0.f,0.f,0.f},{0.f,0.f,0.f,0.f},
                            {0.f,0.f,0.f,0.f},{0.f,0.f,0.f,0.f}};
            #pragma unroll
            for (int kc = 0; kc < 4; ++kc) {
                short8 afr = *(const short8*)(&As[w * 16 + lr][kc * 32 + quad * 8]);
                #pragma unroll
                for (int n4 = 0; n4 < 4; ++n4) {
                    short8 bfr = *(const short8*)(&Bs[n4 * 16 + lr][kc * 32 + quad * 8]);
                    acc[n4] = __builtin_amdgcn_mfma_f32_16x16x32_bf16(bfr, afr, acc[n4], 0, 0, 0);
                }
            }
            if (ct < 2) {
                unsigned short* dst = qb + (size_t)row * 128 + ct * 64;
                #pragma unroll
                for (int n4 = 0; n4 < 4; ++n4) {
                    int colb = n4 * 16 + quad * 4;
                    float4 bv = *(const float4*)(bias2 + ct * 64 + colb);
                    ushort4 o;
                    o.x = f2h(acc[n4][0] + bv.x);
                    o.y = f2h(acc[n4][1] + bv.y);
                    o.z = f2h(acc[n4][2] + bv.z);
                    o.w = f2h(acc[n4][3] + bv.w);
                    *(ushort4*)(dst + colb) = o;
                }
            } else {
                unsigned char* dstrow = kvb + (size_t)row * 256;
                int isV = (ct >= 4);
                int hbase = (ct - (isV ? 4 : 2)) * 4;
                #pragma unroll
                for (int n4 = 0; n4 < 4; ++n4) {
                    float4 bv = *(const float4*)(bias2 + ct * 64 + n4 * 16 + quad * 4);
                    int off = (hbase + n4) * 32 + isV * 16 + quad * 4;
                    *(unsigned int*)(dstrow + off) = f32x4_to_fp8(
                        acc[n4][0] + bv.x, acc[n4][1] + bv.y,
                        acc[n4][2] + bv.z, acc[n4][3] + bv.w);
                }
            }
        }
    } else {
        #pragma unroll
        for (int i = 0; i < 4; ++i) {
            int idx = t + i * 256;
            int r = idx >> 4;
            int c8 = (idx & 15) * 8;
            *(u16x8*)(&Bs[r][c8]) = *(const u16x8*)(W2T + (size_t)r * 128 + c8);
        }
        __syncthreads();
        f32x4 acc[4] = {{0.f,0.f,0.f,0.f},{0.f,0.f,0.f,0.f},
                        {0.f,0.f,0.f,0.f},{0.f,0.f,0.f,0.f}};
        #pragma unroll
        for (int kc = 0; kc < 4; ++kc) {
            short8 afr = *(const short8*)(&As[w * 16 + lr][kc * 32 + quad * 8]);
            #pragma unroll
            for (int n4 = 0; n4 < 4; ++n4) {
                short8 bfr = *(const short8*)(&Bs[n4 * 16 + lr][kc * 32 + quad * 8]);
                acc[n4] = __builtin_amdgcn_mfma_f32_16x16x32_bf16(bfr, afr, acc[n4], 0, 0, 0);
            }
        }
        #pragma unroll
        for (int n4 = 0; n4 < 4; ++n4) {
            int colb = n4 * 16 + quad * 4;
            float4 bv = *(const float4*)(bias2 + colb);
            float4 o;
            o.x = acc[n4][0] + bv.x;
            o.y = acc[n4][1] + bv.y;
            o.z = acc[n4][2] + bv.z;
            o.w = acc[n4][3] + bv.w;
            *(float4*)(outF + (size_t)row * 64 + colb) = o;
        }
    }
}

// ---------------- Fused per-destination softmax + aggregation --------------------
// kvb rows 256 B, per-head interleave: lane reads k at h*32, v at h*32+16 (same line).
__global__ __launch_bounds__(256) void aggregate_kernel(
    const unsigned short* __restrict__ qb, const unsigned char* __restrict__ kvb,
    const int* __restrict__ podeg,
    const int* __restrict__ srcSorted, unsigned short* __restrict__ aggb)
{
    int n = (blockIdx.x * 256 + threadIdx.x) >> 6;
    int lane = threadIdx.x & 63;
    int es = lane >> 3;
    int h = lane & 7;

    float qf[16];
    {
        kv8 a, b;
        a.u = *(const u16x8*)(qb + (size_t)n * 128 + h * 16);
        b.u = *(const u16x8*)(qb + (size_t)n * 128 + h * 16 + 8);
        #pragma unroll
        for (int j = 0; j < 8; ++j) { qf[j] = (float)a.h[j]; qf[8 + j] = (float)b.h[j]; }
    }
    float acc[16];
    #pragma unroll
    for (int j = 0; j < 16; ++j) acc[j] = 0.f;
    float den = 0.f;

    int pd = podeg[n];
    int start = pd & 0xFFFFF;
    int d = ((unsigned)pd) >> 20;
    if (d > 0) {
        int ng = (d + 7) >> 3;
        int lastIdx = start + d - 1;

        int4 kA, vA, kB, vB;
        {
            int i0 = start + es; if (i0 > lastIdx) i0 = lastIdx;
            const unsigned char* p = kvb + (size_t)srcSorted[i0] * 256 + h * 32;
            kA = *(const int4*)p;
            vA = *(const int4*)(p + 16);
        }
        kB = kA; vB = vA;
        if (ng > 1) {
            int i1 = start + 8 + es; if (i1 > lastIdx) i1 = lastIdx;
            const unsigned char* p = kvb + (size_t)srcSorted[i1] * 256 + h * 32;
            kB = *(const int4*)p;
            vB = *(const int4*)(p + 16);
        }

        for (int g = 0; g < ng; ++g) {
            int4 kC = kA, vC = vA;
            if (g + 2 < ng) {
                int ni = start + (g + 2) * 8 + es; if (ni > lastIdx) ni = lastIdx;
                const unsigned char* p = kvb + (size_t)srcSorted[ni] * 256 + h * 32;
                kC = *(const int4*)p;
                vC = *(const int4*)(p + 16);
            }
            float pdot = 0.f;
            {
                float kf[16];
                fp8x4_to_f32((unsigned int)kA.x, kf);
                fp8x4_to_f32((unsigned int)kA.y, kf + 4);
                fp8x4_to_f32((unsigned int)kA.z, kf + 8);
                fp8x4_to_f32((unsigned int)kA.w, kf + 12);
                #pragma unroll
                for (int j = 0; j < 16; ++j) pdot = fmaf(kf[j], qf[j], pdot);
            }
            float ev = (g * 8 + es < d) ? fast_exp2(pdot) : 0.f;
            den += ev;
            {
                float vf[16];
                fp8x4_to_f32((unsigned int)vA.x, vf);
                fp8x4_to_f32((unsigned int)vA.y, vf + 4);
                fp8x4_to_f32((unsigned int)vA.z, vf + 8);
                fp8x4_to_f32((unsigned int)vA.w, vf + 12);
                #pragma unroll
                for (int j = 0; j < 16; ++j) acc[j] = fmaf(vf[j], ev, acc[j]);
            }
            kA = kB; vA = vB;
            kB = kC; vB = vC;
        }
    }
    #pragma unroll
    for (int m = 8; m < 64; m <<= 1) {
        den += __shfl_xor(den, m, 64);
        #pragma unroll
        for (int j = 0; j < 16; ++j) acc[j] += __shfl_xor(acc[j], m, 64);
    }
    if (es == 0) {
        float w = 1.f / (den + 1e-16f);
        u16x8 o0, o1;
        #pragma unroll
        for (int j = 0; j < 8; ++j) {
            o0[j] = f2bf(acc[j] * w);
            o1[j] = f2bf(acc[j + 8] * w);
        }
        *(u16x8*)(aggb + (size_t)n * 128 + h * 16) = o0;
        *(u16x8*)(aggb + (size_t)n * 128 + h * 16 + 8) = o1;
    }
}

extern "C" void kernel_launch(void* const* d_in, const int* in_sizes, int n_in,
                              void* d_out, int out_size, void* d_ws, size_t ws_size,
                              hipStream_t stream) {
    const float* x     = (const float*)d_in[0];
    const int*   eidx  = (const int*)d_in[1];
    const float* Wk    = (const float*)d_in[2];
    const float* bk    = (const float*)d_in[3];
    const float* Wq    = (const float*)d_in[4];
    const float* bq    = (const float*)d_in[5];
    const float* Wv    = (const float*)d_in[6];
    const float* bv    = (const float*)d_in[7];
    const float* a_rel = (const float*)d_in[8];
    const float* m_rel = (const float*)d_in[9];
    const float* p_rel = (const float*)d_in[10];
    const float* skip  = (const float*)d_in[11];
    const float* aW    = (const float*)d_in[12];
    const float* ab    = (const float*)d_in[13];
    const float* fcW   = (const float*)d_in[14];
    const float* fcb   = (const float*)d_in[15];
    float* out = (float*)d_out;

    float* biasf = (float*)d_ws;                              // 2*384
    unsigned short* hb   = (unsigned short*)(biasf + 768);    // NN*128 bf16
    unsigned short* qb   = hb + (size_t)NN * 128;             // NN*128 f16
    unsigned char*  kvb  = (unsigned char*)(qb + (size_t)NN * 128); // NN*256 B fp8
    unsigned short* aggb = (unsigned short*)(kvb + (size_t)NN * 256); // NN*128 bf16
    unsigned short* BfT  = aggb + (size_t)NN * 128;           // 2*384*128
    unsigned short* aWT  = BfT + 2 * 384 * 128;               // 2*128*128
    unsigned short* fcWT = aWT + 2 * 128 * 128;               // 64*128
    int* podeg     = (int*)(fcWT + 64 * 128);                 // NN (offs | deg<<20)
    int* gcur      = podeg + NN;                              // NCO (pad 160)
    int* ebuk      = gcur + 160;                              // NCO*BCAP
    int* srcSorted = ebuk + NCO * BCAP;                       // NCO*BCAP

    // zero the coarse-bucket cursors (captured as a graph memset node)
    hipMemsetAsync(gcur, 0, NCO * sizeof(int), stream);

    // weights + coarse scatter (one dispatch, disjoint block ranges)
    prep_kernel<<<P1B + WBLOCKS, 256, 0, stream>>>(
        Wq, bq, Wk, bk, a_rel, Wv, bv, m_rel, p_rel, aW, fcW,
        BfT, biasf, aWT, fcWT, eidx, gcur, ebuk);

    // layer-0 QKV GEMM + CSR pass 3 (co-scheduled)
    qkv0_p3_kernel<<<GBLOCKS + NCO, 256, 0, stream>>>(
        x, BfT, biasf, qb, kvb, gcur, ebuk, podeg, srcSorted);

    aggregate_kernel<<<NN / 4, 256, 0, stream>>>(qb, kvb, podeg, srcSorted, aggb);

    // out-GEMM(L0) -> h0 -> QKV(L1) (qb/kvb overwritten in place; agg L0 done)
    fused_kernel<0, 0><<<GBLOCKS, 256, 0, stream>>>(
        aggb, aWT, ab, skip, x, nullptr, hb,
        BfT + 49152, biasf + 384, qb, kvb, nullptr);

    aggregate_kernel<<<NN / 4, 256, 0, stream>>>(qb, kvb, podeg, srcSorted, aggb);

    // out-GEMM(L1) -> h1 (LDS) -> fc -> out
    fused_kernel<1, 2><<<GBLOCKS, 256, 0, stream>>>(
        aggb, aWT + 16384, ab + 128, skip + 1, nullptr, hb, nullptr,
        fcWT, fcb, nullptr, nullptr, out);
}

// Round 6
// 242.482 us; speedup vs baseline: 1.1385x; 1.0119x over previous
//
#include <hip/hip_runtime.h>
#include <hip/hip_bf16.h>
#include <math.h>

#define NN 40000
#define NE 640000

typedef __attribute__((ext_vector_type(8))) short short8;
typedef __attribute__((ext_vector_type(8))) unsigned short u16x8;
typedef __attribute__((ext_vector_type(4))) float f32x4;
typedef __attribute__((ext_vector_type(2))) float f32v2;
typedef _Float16 h16x2 __attribute__((ext_vector_type(2)));

#define WBLOCKS 547   // weight-prep blocks
#define GBLOCKS 625   // GEMM row blocks (NN/64)
#define NCO 157       // coarse buckets (dst>>8)
#define P1B 160       // scatter blocks
#define EPB 4000      // edges per scatter block (NE/P1B)
#define BCAP 5120     // padded capacity per coarse bucket (16 sigma margin)

#if __has_builtin(__builtin_amdgcn_cvt_pk_f32_fp8) && __has_builtin(__builtin_amdgcn_cvt_pk_fp8_f32)
#define HAS_FP8CVT 1
#else
#define HAS_FP8CVT 0
#endif

__device__ __forceinline__ float fast_exp2(float x) {
#if __has_builtin(__builtin_amdgcn_exp2f)
    return __builtin_amdgcn_exp2f(x);
#else
    return exp2f(x);
#endif
}

// tanh-gelu, mathematically identical to 0.5x(1+tanh(u)) via tanh(u)=1-2/(1+e^{2u})
__device__ __forceinline__ float gelu_tanh(float x) {
    float x3 = x * x * x;
    float u = 0.7978845608028654f * (x + 0.044715f * x3);
    float t = 1.0f - 2.0f / (1.0f + fast_exp2(2.885390081777927f * u));
    return 0.5f * x * (1.0f + t);
}

__device__ __forceinline__ unsigned short f2bf(float v) {
    __hip_bfloat16 h = __float2bfloat16(v);
    return *reinterpret_cast<unsigned short*>(&h);
}

__device__ __forceinline__ unsigned short f2h(float v) {
    union { _Float16 h; unsigned short u; } c;
    c.h = (_Float16)v;
    return c.u;
}

__device__ __forceinline__ float bf2f(unsigned short u) {
    union { unsigned int i; float f; } c;
    c.i = ((unsigned int)u) << 16;
    return c.f;
}

// ---------------- fp8 e4m3 pack/unpack --------------------------------------
#if HAS_FP8CVT
__device__ __forceinline__ unsigned int f32x4_to_fp8(float a, float b, float c, float d) {
    int r = 0;
    r = __builtin_amdgcn_cvt_pk_fp8_f32(a, b, r, false);
    r = __builtin_amdgcn_cvt_pk_fp8_f32(c, d, r, true);
    return (unsigned int)r;
}
__device__ __forceinline__ void fp8x4_to_f32(unsigned int w, float* o) {
    f32v2 lo = __builtin_amdgcn_cvt_pk_f32_fp8((int)w, false);
    f32v2 hi = __builtin_amdgcn_cvt_pk_f32_fp8((int)w, true);
    o[0] = lo[0]; o[1] = lo[1]; o[2] = hi[0]; o[3] = hi[1];
}
#else
__device__ __forceinline__ unsigned char f2fp8_sw(float x) {
    union { float f; unsigned u; } c; c.f = x;
    unsigned sgn = (c.u >> 31) << 7;
    c.u &= 0x7fffffffu;
    if (!(c.f < 464.f)) return (unsigned char)(sgn | 0x7e);
    if (c.f < 0.0009765625f) return (unsigned char)sgn;
    if (c.f < 0.015625f) {
        int q = (int)rintf(c.f * 512.f);
        if (q > 7) return (unsigned char)(sgn | 0x08);
        return (unsigned char)(sgn | q);
    }
    unsigned u = c.u;
    unsigned lsb = (u >> 20) & 1;
    u += 0x7ffffu + lsb;
    int e8 = (int)(u >> 23) - 127 + 7;
    if (e8 > 15) return (unsigned char)(sgn | 0x7e);
    unsigned m = (u >> 20) & 7;
    return (unsigned char)(sgn | (e8 << 3) | m);
}
__device__ __forceinline__ float fp8_to_f32_sw(unsigned char b) {
    int e = (b >> 3) & 15, m = b & 7;
    float v = (e == 0) ? ldexpf((float)m, -9) : ldexpf(8.0f + (float)m, e - 10);
    return (b & 0x80) ? -v : v;
}
__device__ __forceinline__ unsigned int f32x4_to_fp8(float a, float b, float c, float d) {
    return (unsigned int)f2fp8_sw(a) | ((unsigned int)f2fp8_sw(b) << 8) |
           ((unsigned int)f2fp8_sw(c) << 16) | ((unsigned int)f2fp8_sw(d) << 24);
}
__device__ __forceinline__ void fp8x4_to_f32(unsigned int w, float* o) {
    o[0] = fp8_to_f32_sw((unsigned char)(w & 0xff));
    o[1] = fp8_to_f32_sw((unsigned char)((w >> 8) & 0xff));
    o[2] = fp8_to_f32_sw((unsigned char)((w >> 16) & 0xff));
    o[3] = fp8_to_f32_sw((unsigned char)((w >> 24) & 0xff));
}
#endif

union kv8 { u16x8 u; h16x2 p[4]; _Float16 h[8]; };
union frag8 { short8 s; unsigned short u[8]; u16x8 v; };

// ---- merged: coarse scatter w/ atomic range reservation (blocks 0..P1B-1) ----
// ---- + weight prep (blocks P1B..P1B+WBLOCKS-1) --------------------------------
__global__ __launch_bounds__(256) void prep_kernel(
    const float* __restrict__ Wq, const float* __restrict__ bq,
    const float* __restrict__ Wk, const float* __restrict__ bk,
    const float* __restrict__ a_rel,
    const float* __restrict__ Wv, const float* __restrict__ bv,
    const float* __restrict__ m_rel,
    const float* __restrict__ p_rel,
    const float* __restrict__ aW, const float* __restrict__ fcW,
    unsigned short* __restrict__ BfT, float* __restrict__ biasf,
    unsigned short* __restrict__ aWT, unsigned short* __restrict__ fcWT,
    const int* __restrict__ eidx, int* __restrict__ gcur, int* __restrict__ ebuk)
{
    if (blockIdx.x < P1B) {
        __shared__ int cnt[NCO];
        __shared__ int cur[NCO];
        int b = blockIdx.x;
        int t = threadIdx.x;
        if (t < NCO) cnt[t] = 0;
        __syncthreads();
        int bs = b * EPB;
        for (int e = bs + t; e < bs + EPB; e += 256)
            atomicAdd(&cnt[eidx[NE + e] >> 8], 1);
        __syncthreads();
        if (t < NCO) cur[t] = atomicAdd(&gcur[t], cnt[t]);
        __syncthreads();
        for (int e = bs + t; e < bs + EPB; e += 256) {
            int s = eidx[e];
            int d = eidx[NE + e];
            int cb = d >> 8;
            int pos = atomicAdd(&cur[cb], 1);
            ebuk[cb * BCAP + pos] = ((d & 255) << 16) | s;
        }
        return;
    }
    int idx = (blockIdx.x - P1B) * 256 + threadIdx.x;
    if (idx < 2 * 129 * 384) {
        int l = idx / (129 * 384);
        int j = idx - l * (129 * 384);
        int r = j / 384;
        int col = j - r * 384;
        const float* Wq_l = Wq + l * 16384;
        const float* Wk_l = Wk + l * 16384;
        const float* Wv_l = Wv + l * 16384;
        const float* ar_l = a_rel + l * 2048;
        const float* mr_l = m_rel + l * 2048;
        float val;
        if (col < 128) {
            val = (r < 128) ? Wq_l[r * 128 + col] : bq[l * 128 + col];
        } else if (col < 256) {
            int cc = col - 128; int h = cc >> 4; int eo = cc & 15;
            float scale = p_rel[l * 8 + h] * 0.25f * 1.4426950408889634f;
            float s = 0.f;
            #pragma unroll
            for (int d = 0; d < 16; ++d) {
                float w = (r < 128) ? Wk_l[r * 128 + h * 16 + d] : bk[l * 128 + h * 16 + d];
                s += w * ar_l[h * 256 + d * 16 + eo];
            }
            val = s * scale;
        } else {
            int cc = col - 256; int h = cc >> 4; int eo = cc & 15;
            float s = 0.f;
            #pragma unroll
            for (int d = 0; d < 16; ++d) {
                float w = (r < 128) ? Wv_l[r * 128 + h * 16 + d] : bv[l * 128 + h * 16 + d];
                s += w * mr_l[h * 256 + d * 16 + eo];
            }
            val = s;
        }
        if (r < 128) BfT[(size_t)l * 49152 + (size_t)col * 128 + r] = f2bf(val);
        else         biasf[l * 384 + col] = val;
    } else if (idx < 2 * 129 * 384 + 2 * 16384) {
        int i = idx - 2 * 129 * 384;
        int l = i >> 14; int j = i & 16383;
        int r = j >> 7, c = j & 127;
        aWT[(size_t)l * 16384 + (size_t)c * 128 + r] = f2bf(aW[(size_t)l * 16384 + r * 128 + c]);
    } else {
        int i = idx - (2 * 129 * 384 + 2 * 16384);
        int c = i >> 7, r = i & 127;
        fcWT[(size_t)c * 128 + r] = f2bf(fcW[(size_t)r * 64 + c]);
    }
}

// ---- qkv0 GEMM (blocks 0..624) + CSR pass 3 (blocks 625..781) -------------------
// qb rows: f16 [NN][128].  kvb rows: [k fp8 (128 B) | v fp8 (128 B)], 256 B.
// B-tile staging uses T14 issue-early/write-late (regs -> LDS after compute).
__global__ __launch_bounds__(256) void qkv0_p3_kernel(
    const float* __restrict__ Af, const unsigned short* __restrict__ BT,
    const float* __restrict__ bias,
    unsigned short* __restrict__ qb, unsigned char* __restrict__ kvb,
    const int* __restrict__ gcnt, const int* __restrict__ ebuk,
    int* __restrict__ podeg, int* __restrict__ srcSorted)
{
    if (blockIdx.x >= GBLOCKS) {
        // pass 3: fine grouping within one coarse bucket, LDS only
        __shared__ int hist[256], loffs[256], cur[256];
        int c = blockIdx.x - GBLOCKS;
        int t = threadIdx.x;
        int base = c * BCAP;
        int end = base + gcnt[c];
        hist[t] = 0;
        __syncthreads();
        for (int i = base + t; i < end; i += 256)
            atomicAdd(&hist[ebuk[i] >> 16], 1);
        __syncthreads();
        int v = hist[t];
        loffs[t] = v;
        __syncthreads();
        #pragma unroll
        for (int off = 1; off < 256; off <<= 1) {
            int u = (t >= off) ? loffs[t - off] : 0;
            __syncthreads();
            loffs[t] += u;
            __syncthreads();
        }
        int excl = loffs[t] - v;
        int n = c * 256 + t;
        if (n < NN) podeg[n] = (base + excl) | (v << 20);
        cur[t] = excl;
        __syncthreads();
        for (int i = base + t; i < end; i += 256) {
            int p = ebuk[i];
            int pos = atomicAdd(&cur[p >> 16], 1);
            srcSorted[base + pos] = p & 0xffff;
        }
        return;
    }
    __shared__ unsigned short Bs[64][136];
    int t = threadIdx.x;
    int row0 = blockIdx.x * 64;
    int w = t >> 6;
    int lr = t & 15;
    int quad = (t & 63) >> 4;
    int row = row0 + w * 16 + lr;
    int sr = t >> 4;            // staging row for chunk i: sr + i*16? no: idx-based below
    int sc8 = (t & 15) * 8;

    frag8 af[4];
    {
        const float* ap = Af + (size_t)row * 128 + quad * 8;
        #pragma unroll
        for (int kc = 0; kc < 4; ++kc) {
            float4 a0 = *(const float4*)(ap + kc * 32);
            float4 a1 = *(const float4*)(ap + kc * 32 + 4);
            af[kc].u[0] = f2bf(a0.x); af[kc].u[1] = f2bf(a0.y);
            af[kc].u[2] = f2bf(a0.z); af[kc].u[3] = f2bf(a0.w);
            af[kc].u[4] = f2bf(a1.x); af[kc].u[5] = f2bf(a1.y);
            af[kc].u[6] = f2bf(a1.z); af[kc].u[7] = f2bf(a1.w);
        }
    }

    u16x8 stg[4];
    // prologue: stage ct=0
    #pragma unroll
    for (int i = 0; i < 4; ++i)
        stg[i] = *(const u16x8*)(BT + (size_t)(sr + i * 16) * 128 + sc8);
    #pragma unroll
    for (int i = 0; i < 4; ++i)
        *(u16x8*)(&Bs[sr + i * 16][sc8]) = stg[i];
    __syncthreads();

    #pragma unroll
    for (int ct = 0; ct < 6; ++ct) {
        // issue next tile's loads before compute (T14)
        if (ct < 5) {
            #pragma unroll
            for (int i = 0; i < 4; ++i)
                stg[i] = *(const u16x8*)(BT + (size_t)((ct + 1) * 64 + sr + i * 16) * 128 + sc8);
        }
        f32x4 acc[4] = {{0.f,0.f,0.f,0.f},{0.f,0.f,0.f,0.f},
                        {0.f,0.f,0.f,0.f},{0.f,0.f,0.f,0.f}};
        #pragma unroll
        for (int kc = 0; kc < 4; ++kc) {
            #pragma unroll
            for (int n4 = 0; n4 < 4; ++n4) {
                short8 bfr = *(const short8*)(&Bs[n4 * 16 + lr][kc * 32 + quad * 8]);
                acc[n4] = __builtin_amdgcn_mfma_f32_16x16x32_bf16(bfr, af[kc].s, acc[n4], 0, 0, 0);
            }
        }
        if (ct < 2) {
            unsigned short* dst = qb + (size_t)row * 128 + ct * 64;
            #pragma unroll
            for (int n4 = 0; n4 < 4; ++n4) {
                int colb = n4 * 16 + quad * 4;
                float4 bv = *(const float4*)(bias + ct * 64 + colb);
                ushort4 o;
                o.x = f2h(acc[n4][0] + bv.x);
                o.y = f2h(acc[n4][1] + bv.y);
                o.z = f2h(acc[n4][2] + bv.z);
                o.w = f2h(acc[n4][3] + bv.w);
                *(ushort4*)(dst + colb) = o;
            }
        } else {
            unsigned char* dst = kvb + (size_t)row * 256 + (ct - 2) * 64;
            #pragma unroll
            for (int n4 = 0; n4 < 4; ++n4) {
                int colb = n4 * 16 + quad * 4;
                float4 bv = *(const float4*)(bias + ct * 64 + colb);
                *(unsigned int*)(dst + colb) = f32x4_to_fp8(
                    acc[n4][0] + bv.x, acc[n4][1] + bv.y,
                    acc[n4][2] + bv.z, acc[n4][3] + bv.w);
            }
        }
        __syncthreads();               // all Bs reads done
        if (ct < 5) {
            #pragma unroll
            for (int i = 0; i < 4; ++i)
                *(u16x8*)(&Bs[sr + i * 16][sc8]) = stg[i];
            __syncthreads();           // Bs ct+1 ready
        }
    }
}

// Fused: out-GEMM (gelu(agg)@aWT + skip -> h) then second GEMM from h (in LDS).
// T14 staging throughout.
template <int HPFMT, int P2>
__global__ __launch_bounds__(256) void fused_kernel(
    const unsigned short* __restrict__ aggb,
    const unsigned short* __restrict__ aWT, const float* __restrict__ ab,
    const float* __restrict__ skip_p,
    const float* __restrict__ HprevF, const unsigned short* __restrict__ HprevB,
    unsigned short* __restrict__ hb_out,
    const unsigned short* __restrict__ W2T, const float* __restrict__ bias2,
    unsigned short* __restrict__ qb, unsigned char* __restrict__ kvb,
    float* __restrict__ outF)
{
    __shared__ unsigned short As[64][136];
    __shared__ unsigned short Bs[64][136];
    int t = threadIdx.x;
    int row0 = blockIdx.x * 64;
    int w = t >> 6;
    int lr = t & 15;
    int quad = (t & 63) >> 4;
    int row = row0 + w * 16 + lr;
    int sr = t >> 4;
    int sc8 = (t & 15) * 8;

    frag8 agf[4];
    {
        const unsigned short* ap = aggb + (size_t)row * 128 + quad * 8;
        #pragma unroll
        for (int kc = 0; kc < 4; ++kc) {
            u16x8 u = *(const u16x8*)(ap + kc * 32);
            #pragma unroll
            for (int j = 0; j < 8; ++j) agf[kc].u[j] = f2bf(gelu_tanh(bf2f(u[j])));
        }
    }

    float sv = skip_p[0];
    float beta = 1.f / (1.f + expf(-sv));
    float omb = 1.f - beta;

    u16x8 stg[4];
    // prologue: stage aWT ct=0
    #pragma unroll
    for (int i = 0; i < 4; ++i)
        stg[i] = *(const u16x8*)(aWT + (size_t)(sr + i * 16) * 128 + sc8);
    #pragma unroll
    for (int i = 0; i < 4; ++i)
        *(u16x8*)(&Bs[sr + i * 16][sc8]) = stg[i];
    __syncthreads();

    f32x4 hacc[2][4];
    // ---- phase B ct=0 ----
    #pragma unroll
    for (int i = 0; i < 4; ++i)   // issue aWT ct=1 loads
        stg[i] = *(const u16x8*)(aWT + (size_t)(64 + sr + i * 16) * 128 + sc8);
    #pragma unroll
    for (int n4 = 0; n4 < 4; ++n4) hacc[0][n4] = (f32x4){0.f,0.f,0.f,0.f};
    #pragma unroll
    for (int kc = 0; kc < 4; ++kc) {
        #pragma unroll
        for (int n4 = 0; n4 < 4; ++n4) {
            short8 bfr = *(const short8*)(&Bs[n4 * 16 + lr][kc * 32 + quad * 8]);
            hacc[0][n4] = __builtin_amdgcn_mfma_f32_16x16x32_bf16(bfr, agf[kc].s, hacc[0][n4], 0, 0, 0);
        }
    }
    __syncthreads();
    #pragma unroll
    for (int i = 0; i < 4; ++i)
        *(u16x8*)(&Bs[sr + i * 16][sc8]) = stg[i];
    __syncthreads();
    // ---- phase B ct=1 (issue W2T tile-0 loads during compute) ----
    #pragma unroll
    for (int i = 0; i < 4; ++i)
        stg[i] = *(const u16x8*)(W2T + (size_t)(sr + i * 16) * 128 + sc8);
    #pragma unroll
    for (int n4 = 0; n4 < 4; ++n4) hacc[1][n4] = (f32x4){0.f,0.f,0.f,0.f};
    #pragma unroll
    for (int kc = 0; kc < 4; ++kc) {
        #pragma unroll
        for (int n4 = 0; n4 < 4; ++n4) {
            short8 bfr = *(const short8*)(&Bs[n4 * 16 + lr][kc * 32 + quad * 8]);
            hacc[1][n4] = __builtin_amdgcn_mfma_f32_16x16x32_bf16(bfr, agf[kc].s, hacc[1][n4], 0, 0, 0);
        }
    }

    // ---- h = relu(beta*(out+ab) + (1-beta)*hprev) -> As (+hb for P2==0) ----
    #pragma unroll
    for (int ct = 0; ct < 2; ++ct) {
        #pragma unroll
        for (int n4 = 0; n4 < 4; ++n4) {
            int colb = ct * 64 + n4 * 16 + quad * 4;
            float4 bv = *(const float4*)(ab + colb);
            float hp[4];
            if (HPFMT == 0) {
                float4 h4 = *(const float4*)(HprevF + (size_t)row * 128 + colb);
                hp[0] = h4.x; hp[1] = h4.y; hp[2] = h4.z; hp[3] = h4.w;
            } else {
                ushort4 h4 = *(const ushort4*)(HprevB + (size_t)row * 128 + colb);
                hp[0] = bf2f(h4.x); hp[1] = bf2f(h4.y); hp[2] = bf2f(h4.z); hp[3] = bf2f(h4.w);
            }
            ushort4 o;
            o.x = f2bf(fmaxf(beta * (hacc[ct][n4][0] + bv.x) + omb * hp[0], 0.f));
            o.y = f2bf(fmaxf(beta * (hacc[ct][n4][1] + bv.y) + omb * hp[1], 0.f));
            o.z = f2bf(fmaxf(beta * (hacc[ct][n4][2] + bv.z) + omb * hp[2], 0.f));
            o.w = f2bf(fmaxf(beta * (hacc[ct][n4][3] + bv.w) + omb * hp[3], 0.f));
            *(ushort4*)(&As[w * 16 + lr][colb]) = o;
            if (P2 == 0) *(ushort4*)(hb_out + (size_t)row * 128 + colb) = o;
        }
    }
    __syncthreads();                   // phase-B Bs reads done everywhere
    #pragma unroll
    for (int i = 0; i < 4; ++i)        // Bs <- W2T tile 0 (loads long since issued)
        *(u16x8*)(&Bs[sr + i * 16][sc8]) = stg[i];
    __syncthreads();

    // ---------- phase C: h @ W2T ----------
    if (P2 == 0) {
        #pragma unroll
        for (int ct = 0; ct < 6; ++ct) {
            if (ct < 5) {
                #pragma unroll
                for (int i = 0; i < 4; ++i)
                    stg[i] = *(const u16x8*)(W2T + (size_t)((ct + 1) * 64 + sr + i * 16) * 128 + sc8);
            }
            f32x4 acc[4] = {{0.f,0.f,0.f,0.f},{0.f,0.f,0.f,0.f},
                            {0.f,0.f,0.f,0.f},{0.f,0.f,0.f,0.f}};
            #pragma unroll
            for (int kc = 0; kc < 4; ++kc) {
                short8 afr = *(const short8*)(&As[w * 16 + lr][kc * 32 + quad * 8]);
                #pragma unroll
                for (int n4 = 0; n4 < 4; ++n4) {
                    short8 bfr = *(const short8*)(&Bs[n4 * 16 + lr][kc * 32 + quad * 8]);
                    acc[n4] = __builtin_amdgcn_mfma_f32_16x16x32_bf16(bfr, afr, acc[n4], 0, 0, 0);
                }
            }
            if (ct < 2) {
                unsigned short* dst = qb + (size_t)row * 128 + ct * 64;
                #pragma unroll
                for (int n4 = 0; n4 < 4; ++n4) {
                    int colb = n4 * 16 + quad * 4;
                    float4 bv = *(const float4*)(bias2 + ct * 64 + colb);
                    ushort4 o;
                    o.x = f2h(acc[n4][0] + bv.x);
                    o.y = f2h(acc[n4][1] + bv.y);
                    o.z = f2h(acc[n4][2] + bv.z);
                    o.w = f2h(acc[n4][3] + bv.w);
                    *(ushort4*)(dst + colb) = o;
                }
            } else {
                unsigned char* dst = kvb + (size_t)row * 256 + (ct - 2) * 64;
                #pragma unroll
                for (int n4 = 0; n4 < 4; ++n4) {
                    int colb = n4 * 16 + quad * 4;
                    float4 bv = *(const float4*)(bias2 + ct * 64 + colb);
                    *(unsigned int*)(dst + colb) = f32x4_to_fp8(
                        acc[n4][0] + bv.x, acc[n4][1] + bv.y,
                        acc[n4][2] + bv.z, acc[n4][3] + bv.w);
                }
            }
            __syncthreads();
            if (ct < 5) {
                #pragma unroll
                for (int i = 0; i < 4; ++i)
                    *(u16x8*)(&Bs[sr + i * 16][sc8]) = stg[i];
                __syncthreads();
            }
        }
    } else {
        f32x4 acc[4] = {{0.f,0.f,0.f,0.f},{0.f,0.f,0.f,0.f},
                        {0.f,0.f,0.f,0.f},{0.f,0.f,0.f,0.f}};
        #pragma unroll
        for (int kc = 0; kc < 4; ++kc) {
            short8 afr = *(const short8*)(&As[w * 16 + lr][kc * 32 + quad * 8]);
            #pragma unroll
            for (int n4 = 0; n4 < 4; ++n4) {
                short8 bfr = *(const short8*)(&Bs[n4 * 16 + lr][kc * 32 + quad * 8]);
                acc[n4] = __builtin_amdgcn_mfma_f32_16x16x32_bf16(bfr, afr, acc[n4], 0, 0, 0);
            }
        }
        #pragma unroll
        for (int n4 = 0; n4 < 4; ++n4) {
            int colb = n4 * 16 + quad * 4;
            float4 bv = *(const float4*)(bias2 + colb);
            float4 o;
            o.x = acc[n4][0] + bv.x;
            o.y = acc[n4][1] + bv.y;
            o.z = acc[n4][2] + bv.z;
            o.w = acc[n4][3] + bv.w;
            *(float4*)(outF + (size_t)row * 64 + colb) = o;
        }
    }
}

// ---------------- Fused per-destination softmax + aggregation --------------------
// kvb rows 256 B: [k fp8 x128 | v fp8 x128]; per (edge,head) lane: 2x16B loads.
__global__ __launch_bounds__(256) void aggregate_kernel(
    const unsigned short* __restrict__ qb, const unsigned char* __restrict__ kvb,
    const int* __restrict__ podeg,
    const int* __restrict__ srcSorted, unsigned short* __restrict__ aggb)
{
    int n = (blockIdx.x * 256 + threadIdx.x) >> 6;
    int lane = threadIdx.x & 63;
    int es = lane >> 3;
    int h = lane & 7;

    float qf[16];
    {
        kv8 a, b;
        a.u = *(const u16x8*)(qb + (size_t)n * 128 + h * 16);
        b.u = *(const u16x8*)(qb + (size_t)n * 128 + h * 16 + 8);
        #pragma unroll
        for (int j = 0; j < 8; ++j) { qf[j] = (float)a.h[j]; qf[8 + j] = (float)b.h[j]; }
    }
    float acc[16];
    #pragma unroll
    for (int j = 0; j < 16; ++j) acc[j] = 0.f;
    float den = 0.f;

    int pd = podeg[n];
    int start = pd & 0xFFFFF;
    int d = ((unsigned)pd) >> 20;
    if (d > 0) {
        int ng = (d + 7) >> 3;
        int lastIdx = start + d - 1;

        int4 kA, vA, kB, vB;
        {
            int i0 = start + es; if (i0 > lastIdx) i0 = lastIdx;
            const unsigned char* p = kvb + (size_t)srcSorted[i0] * 256 + h * 16;
            kA = *(const int4*)p;
            vA = *(const int4*)(p + 128);
        }
        kB = kA; vB = vA;
        if (ng > 1) {
            int i1 = start + 8 + es; if (i1 > lastIdx) i1 = lastIdx;
            const unsigned char* p = kvb + (size_t)srcSorted[i1] * 256 + h * 16;
            kB = *(const int4*)p;
            vB = *(const int4*)(p + 128);
        }

        for (int g = 0; g < ng; ++g) {
            int4 kC = kA, vC = vA;
            if (g + 2 < ng) {
                int ni = start + (g + 2) * 8 + es; if (ni > lastIdx) ni = lastIdx;
                const unsigned char* p = kvb + (size_t)srcSorted[ni] * 256 + h * 16;
                kC = *(const int4*)p;
                vC = *(const int4*)(p + 128);
            }
            float pdot = 0.f;
            {
                float kf[16];
                fp8x4_to_f32((unsigned int)kA.x, kf);
                fp8x4_to_f32((unsigned int)kA.y, kf + 4);
                fp8x4_to_f32((unsigned int)kA.z, kf + 8);
                fp8x4_to_f32((unsigned int)kA.w, kf + 12);
                #pragma unroll
                for (int j = 0; j < 16; ++j) pdot = fmaf(kf[j], qf[j], pdot);
            }
            float ev = (g * 8 + es < d) ? fast_exp2(pdot) : 0.f;
            den += ev;
            {
                float vf[16];
                fp8x4_to_f32((unsigned int)vA.x, vf);
                fp8x4_to_f32((unsigned int)vA.y, vf + 4);
                fp8x4_to_f32((unsigned int)vA.z, vf + 8);
                fp8x4_to_f32((unsigned int)vA.w, vf + 12);
                #pragma unroll
                for (int j = 0; j < 16; ++j) acc[j] = fmaf(vf[j], ev, acc[j]);
            }
            kA = kB; vA = vB;
            kB = kC; vB = vC;
        }
    }
    #pragma unroll
    for (int m = 8; m < 64; m <<= 1) {
        den += __shfl_xor(den, m, 64);
        #pragma unroll
        for (int j = 0; j < 16; ++j) acc[j] += __shfl_xor(acc[j], m, 64);
    }
    if (es == 0) {
        float w = 1.f / (den + 1e-16f);
        u16x8 o0, o1;
        #pragma unroll
        for (int j = 0; j < 8; ++j) {
            o0[j] = f2bf(acc[j] * w);
            o1[j] = f2bf(acc[j + 8] * w);
        }
        *(u16x8*)(aggb + (size_t)n * 128 + h * 16) = o0;
        *(u16x8*)(aggb + (size_t)n * 128 + h * 16 + 8) = o1;
    }
}

extern "C" void kernel_launch(void* const* d_in, const int* in_sizes, int n_in,
                              void* d_out, int out_size, void* d_ws, size_t ws_size,
                              hipStream_t stream) {
    const float* x     = (const float*)d_in[0];
    const int*   eidx  = (const int*)d_in[1];
    const float* Wk    = (const float*)d_in[2];
    const float* bk    = (const float*)d_in[3];
    const float* Wq    = (const float*)d_in[4];
    const float* bq    = (const float*)d_in[5];
    const float* Wv    = (const float*)d_in[6];
    const float* bv    = (const float*)d_in[7];
    const float* a_rel = (const float*)d_in[8];
    const float* m_rel = (const float*)d_in[9];
    const float* p_rel = (const float*)d_in[10];
    const float* skip  = (const float*)d_in[11];
    const float* aW    = (const float*)d_in[12];
    const float* ab    = (const float*)d_in[13];
    const float* fcW   = (const float*)d_in[14];
    const float* fcb   = (const float*)d_in[15];
    float* out = (float*)d_out;

    float* biasf = (float*)d_ws;                              // 2*384
    unsigned short* hb   = (unsigned short*)(biasf + 768);    // NN*128 bf16
    unsigned short* qb   = hb + (size_t)NN * 128;             // NN*128 f16
    unsigned char*  kvb  = (unsigned char*)(qb + (size_t)NN * 128); // NN*256 B fp8
    unsigned short* aggb = (unsigned short*)(kvb + (size_t)NN * 256); // NN*128 bf16
    unsigned short* BfT  = aggb + (size_t)NN * 128;           // 2*384*128
    unsigned short* aWT  = BfT + 2 * 384 * 128;               // 2*128*128
    unsigned short* fcWT = aWT + 2 * 128 * 128;               // 64*128
    int* podeg     = (int*)(fcWT + 64 * 128);                 // NN (offs | deg<<20)
    int* gcur      = podeg + NN;                              // NCO (pad 160)
    int* ebuk      = gcur + 160;                              // NCO*BCAP
    int* srcSorted = ebuk + NCO * BCAP;                       // NCO*BCAP

    // zero the coarse-bucket cursors (captured as a graph memset node)
    hipMemsetAsync(gcur, 0, NCO * sizeof(int), stream);

    // weights + coarse scatter (one dispatch, disjoint block ranges)
    prep_kernel<<<P1B + WBLOCKS, 256, 0, stream>>>(
        Wq, bq, Wk, bk, a_rel, Wv, bv, m_rel, p_rel, aW, fcW,
        BfT, biasf, aWT, fcWT, eidx, gcur, ebuk);

    // layer-0 QKV GEMM + CSR pass 3 (co-scheduled)
    qkv0_p3_kernel<<<GBLOCKS + NCO, 256, 0, stream>>>(
        x, BfT, biasf, qb, kvb, gcur, ebuk, podeg, srcSorted);

    aggregate_kernel<<<NN / 4, 256, 0, stream>>>(qb, kvb, podeg, srcSorted, aggb);

    // out-GEMM(L0) -> h0 -> QKV(L1) (qb/kvb overwritten in place; agg L0 done)
    fused_kernel<0, 0><<<GBLOCKS, 256, 0, stream>>>(
        aggb, aWT, ab, skip, x, nullptr, hb,
        BfT + 49152, biasf + 384, qb, kvb, nullptr);

    aggregate_kernel<<<NN / 4, 256, 0, stream>>>(qb, kvb, podeg, srcSorted, aggb);

    // out-GEMM(L1) -> h1 (LDS) -> fc -> out
    fused_kernel<1, 2><<<GBLOCKS, 256, 0, stream>>>(
        aggb, aWT + 16384, ab + 128, skip + 1, nullptr, hb, nullptr,
        fcWT, fcb, nullptr, nullptr, out);
}

// Round 7
// 237.987 us; speedup vs baseline: 1.1600x; 1.0189x over previous
//
#include <hip/hip_runtime.h>
#include <hip/hip_bf16.h>
#include <math.h>

#define NN 40000
#define NE 640000

typedef __attribute__((ext_vector_type(8))) short short8;
typedef __attribute__((ext_vector_type(8))) unsigned short u16x8;
typedef __attribute__((ext_vector_type(4))) float f32x4;
typedef __attribute__((ext_vector_type(2))) float f32v2;
typedef _Float16 h16x2 __attribute__((ext_vector_type(2)));

#define WBLOCKS 547   // weight-prep blocks
#define GBLOCKS 625   // GEMM row blocks (NN/64)
#define NCO 157       // coarse buckets (dst>>8)
#define P1B 160       // scatter blocks
#define EPB 4000      // edges per scatter block (NE/P1B)
#define BCAP 5120     // padded capacity per coarse bucket (16 sigma margin)

#if __has_builtin(__builtin_amdgcn_cvt_pk_f32_fp8) && __has_builtin(__builtin_amdgcn_cvt_pk_fp8_f32)
#define HAS_FP8CVT 1
#else
#define HAS_FP8CVT 0
#endif

__device__ __forceinline__ float fast_exp2(float x) {
#if __has_builtin(__builtin_amdgcn_exp2f)
    return __builtin_amdgcn_exp2f(x);
#else
    return exp2f(x);
#endif
}

// tanh-gelu, mathematically identical to 0.5x(1+tanh(u)) via tanh(u)=1-2/(1+e^{2u})
__device__ __forceinline__ float gelu_tanh(float x) {
    float x3 = x * x * x;
    float u = 0.7978845608028654f * (x + 0.044715f * x3);
    float t = 1.0f - 2.0f / (1.0f + fast_exp2(2.885390081777927f * u));
    return 0.5f * x * (1.0f + t);
}

__device__ __forceinline__ unsigned short f2bf(float v) {
    __hip_bfloat16 h = __float2bfloat16(v);
    return *reinterpret_cast<unsigned short*>(&h);
}

__device__ __forceinline__ unsigned short f2h(float v) {
    union { _Float16 h; unsigned short u; } c;
    c.h = (_Float16)v;
    return c.u;
}

__device__ __forceinline__ float bf2f(unsigned short u) {
    union { unsigned int i; float f; } c;
    c.i = ((unsigned int)u) << 16;
    return c.f;
}

// ---------------- fp8 e4m3 pack/unpack --------------------------------------
#if HAS_FP8CVT
__device__ __forceinline__ unsigned int f32x4_to_fp8(float a, float b, float c, float d) {
    int r = 0;
    r = __builtin_amdgcn_cvt_pk_fp8_f32(a, b, r, false);
    r = __builtin_amdgcn_cvt_pk_fp8_f32(c, d, r, true);
    return (unsigned int)r;
}
__device__ __forceinline__ void fp8x4_to_f32(unsigned int w, float* o) {
    f32v2 lo = __builtin_amdgcn_cvt_pk_f32_fp8((int)w, false);
    f32v2 hi = __builtin_amdgcn_cvt_pk_f32_fp8((int)w, true);
    o[0] = lo[0]; o[1] = lo[1]; o[2] = hi[0]; o[3] = hi[1];
}
#else
__device__ __forceinline__ unsigned char f2fp8_sw(float x) {
    union { float f; unsigned u; } c; c.f = x;
    unsigned sgn = (c.u >> 31) << 7;
    c.u &= 0x7fffffffu;
    if (!(c.f < 464.f)) return (unsigned char)(sgn | 0x7e);
    if (c.f < 0.0009765625f) return (unsigned char)sgn;
    if (c.f < 0.015625f) {
        int q = (int)rintf(c.f * 512.f);
        if (q > 7) return (unsigned char)(sgn | 0x08);
        return (unsigned char)(sgn | q);
    }
    unsigned u = c.u;
    unsigned lsb = (u >> 20) & 1;
    u += 0x7ffffu + lsb;
    int e8 = (int)(u >> 23) - 127 + 7;
    if (e8 > 15) return (unsigned char)(sgn | 0x7e);
    unsigned m = (u >> 20) & 7;
    return (unsigned char)(sgn | (e8 << 3) | m);
}
__device__ __forceinline__ float fp8_to_f32_sw(unsigned char b) {
    int e = (b >> 3) & 15, m = b & 7;
    float v = (e == 0) ? ldexpf((float)m, -9) : ldexpf(8.0f + (float)m, e - 10);
    return (b & 0x80) ? -v : v;
}
__device__ __forceinline__ unsigned int f32x4_to_fp8(float a, float b, float c, float d) {
    return (unsigned int)f2fp8_sw(a) | ((unsigned int)f2fp8_sw(b) << 8) |
           ((unsigned int)f2fp8_sw(c) << 16) | ((unsigned int)f2fp8_sw(d) << 24);
}
__device__ __forceinline__ void fp8x4_to_f32(unsigned int w, float* o) {
    o[0] = fp8_to_f32_sw((unsigned char)(w & 0xff));
    o[1] = fp8_to_f32_sw((unsigned char)((w >> 8) & 0xff));
    o[2] = fp8_to_f32_sw((unsigned char)((w >> 16) & 0xff));
    o[3] = fp8_to_f32_sw((unsigned char)((w >> 24) & 0xff));
}
#endif

union kv8 { u16x8 u; h16x2 p[4]; _Float16 h[8]; };
union frag8 { short8 s; unsigned short u[8]; u16x8 v; };

// ---- merged: coarse scatter w/ atomic range reservation (blocks 0..P1B-1) ----
// ---- + weight prep (blocks P1B..P1B+WBLOCKS-1) --------------------------------
__global__ __launch_bounds__(256) void prep_kernel(
    const float* __restrict__ Wq, const float* __restrict__ bq,
    const float* __restrict__ Wk, const float* __restrict__ bk,
    const float* __restrict__ a_rel,
    const float* __restrict__ Wv, const float* __restrict__ bv,
    const float* __restrict__ m_rel,
    const float* __restrict__ p_rel,
    const float* __restrict__ aW, const float* __restrict__ fcW,
    unsigned short* __restrict__ BfT, float* __restrict__ biasf,
    unsigned short* __restrict__ aWT, unsigned short* __restrict__ fcWT,
    const int* __restrict__ eidx, int* __restrict__ gcur, int* __restrict__ ebuk)
{
    if (blockIdx.x < P1B) {
        __shared__ int cnt[NCO];
        __shared__ int cur[NCO];
        int b = blockIdx.x;
        int t = threadIdx.x;
        if (t < NCO) cnt[t] = 0;
        __syncthreads();
        int bs = b * EPB;
        for (int e = bs + t; e < bs + EPB; e += 256)
            atomicAdd(&cnt[eidx[NE + e] >> 8], 1);
        __syncthreads();
        if (t < NCO) cur[t] = atomicAdd(&gcur[t], cnt[t]);
        __syncthreads();
        for (int e = bs + t; e < bs + EPB; e += 256) {
            int s = eidx[e];
            int d = eidx[NE + e];
            int cb = d >> 8;
            int pos = atomicAdd(&cur[cb], 1);
            ebuk[cb * BCAP + pos] = ((d & 255) << 16) | s;
        }
        return;
    }
    int idx = (blockIdx.x - P1B) * 256 + threadIdx.x;
    if (idx < 2 * 129 * 384) {
        int l = idx / (129 * 384);
        int j = idx - l * (129 * 384);
        int r = j / 384;
        int col = j - r * 384;
        const float* Wq_l = Wq + l * 16384;
        const float* Wk_l = Wk + l * 16384;
        const float* Wv_l = Wv + l * 16384;
        const float* ar_l = a_rel + l * 2048;
        const float* mr_l = m_rel + l * 2048;
        float val;
        if (col < 128) {
            val = (r < 128) ? Wq_l[r * 128 + col] : bq[l * 128 + col];
        } else if (col < 256) {
            int cc = col - 128; int h = cc >> 4; int eo = cc & 15;
            float scale = p_rel[l * 8 + h] * 0.25f * 1.4426950408889634f;
            float s = 0.f;
            #pragma unroll
            for (int d = 0; d < 16; ++d) {
                float w = (r < 128) ? Wk_l[r * 128 + h * 16 + d] : bk[l * 128 + h * 16 + d];
                s += w * ar_l[h * 256 + d * 16 + eo];
            }
            val = s * scale;
        } else {
            int cc = col - 256; int h = cc >> 4; int eo = cc & 15;
            float s = 0.f;
            #pragma unroll
            for (int d = 0; d < 16; ++d) {
                float w = (r < 128) ? Wv_l[r * 128 + h * 16 + d] : bv[l * 128 + h * 16 + d];
                s += w * mr_l[h * 256 + d * 16 + eo];
            }
            val = s;
        }
        if (r < 128) BfT[(size_t)l * 49152 + (size_t)col * 128 + r] = f2bf(val);
        else         biasf[l * 384 + col] = val;
    } else if (idx < 2 * 129 * 384 + 2 * 16384) {
        int i = idx - 2 * 129 * 384;
        int l = i >> 14; int j = i & 16383;
        int r = j >> 7, c = j & 127;
        aWT[(size_t)l * 16384 + (size_t)c * 128 + r] = f2bf(aW[(size_t)l * 16384 + r * 128 + c]);
    } else {
        int i = idx - (2 * 129 * 384 + 2 * 16384);
        int c = i >> 7, r = i & 127;
        fcWT[(size_t)c * 128 + r] = f2bf(fcW[(size_t)r * 64 + c]);
    }
}

// ---- qkv0 GEMM (blocks 0..624) + CSR pass 3 (blocks 625..781) -------------------
// qb rows: f16 [NN][128].  kvb rows: [k fp8 (128 B) | v fp8 (128 B)], 256 B.
// B-tile staging uses T14 issue-early/write-late (regs -> LDS after compute).
__global__ __launch_bounds__(256) void qkv0_p3_kernel(
    const float* __restrict__ Af, const unsigned short* __restrict__ BT,
    const float* __restrict__ bias,
    unsigned short* __restrict__ qb, unsigned char* __restrict__ kvb,
    const int* __restrict__ gcnt, const int* __restrict__ ebuk,
    int* __restrict__ podeg, int* __restrict__ srcSorted)
{
    if (blockIdx.x >= GBLOCKS) {
        // pass 3: fine grouping within one coarse bucket, LDS only
        __shared__ int hist[256], loffs[256], cur[256];
        int c = blockIdx.x - GBLOCKS;
        int t = threadIdx.x;
        int base = c * BCAP;
        int end = base + gcnt[c];
        hist[t] = 0;
        __syncthreads();
        for (int i = base + t; i < end; i += 256)
            atomicAdd(&hist[ebuk[i] >> 16], 1);
        __syncthreads();
        int v = hist[t];
        loffs[t] = v;
        __syncthreads();
        #pragma unroll
        for (int off = 1; off < 256; off <<= 1) {
            int u = (t >= off) ? loffs[t - off] : 0;
            __syncthreads();
            loffs[t] += u;
            __syncthreads();
        }
        int excl = loffs[t] - v;
        int n = c * 256 + t;
        if (n < NN) podeg[n] = (base + excl) | (v << 20);
        cur[t] = excl;
        __syncthreads();
        for (int i = base + t; i < end; i += 256) {
            int p = ebuk[i];
            int pos = atomicAdd(&cur[p >> 16], 1);
            srcSorted[base + pos] = p & 0xffff;
        }
        return;
    }
    __shared__ unsigned short Bs[64][136];
    int t = threadIdx.x;
    int row0 = blockIdx.x * 64;
    int w = t >> 6;
    int lr = t & 15;
    int quad = (t & 63) >> 4;
    int row = row0 + w * 16 + lr;
    int sr = t >> 4;
    int sc8 = (t & 15) * 8;

    frag8 af[4];
    {
        const float* ap = Af + (size_t)row * 128 + quad * 8;
        #pragma unroll
        for (int kc = 0; kc < 4; ++kc) {
            float4 a0 = *(const float4*)(ap + kc * 32);
            float4 a1 = *(const float4*)(ap + kc * 32 + 4);
            af[kc].u[0] = f2bf(a0.x); af[kc].u[1] = f2bf(a0.y);
            af[kc].u[2] = f2bf(a0.z); af[kc].u[3] = f2bf(a0.w);
            af[kc].u[4] = f2bf(a1.x); af[kc].u[5] = f2bf(a1.y);
            af[kc].u[6] = f2bf(a1.z); af[kc].u[7] = f2bf(a1.w);
        }
    }

    u16x8 stg[4];
    // prologue: stage ct=0
    #pragma unroll
    for (int i = 0; i < 4; ++i)
        stg[i] = *(const u16x8*)(BT + (size_t)(sr + i * 16) * 128 + sc8);
    #pragma unroll
    for (int i = 0; i < 4; ++i)
        *(u16x8*)(&Bs[sr + i * 16][sc8]) = stg[i];
    __syncthreads();

    #pragma unroll
    for (int ct = 0; ct < 6; ++ct) {
        // issue next tile's loads before compute (T14)
        if (ct < 5) {
            #pragma unroll
            for (int i = 0; i < 4; ++i)
                stg[i] = *(const u16x8*)(BT + (size_t)((ct + 1) * 64 + sr + i * 16) * 128 + sc8);
        }
        f32x4 acc[4] = {{0.f,0.f,0.f,0.f},{0.f,0.f,0.f,0.f},
                        {0.f,0.f,0.f,0.f},{0.f,0.f,0.f,0.f}};
        #pragma unroll
        for (int kc = 0; kc < 4; ++kc) {
            #pragma unroll
            for (int n4 = 0; n4 < 4; ++n4) {
                short8 bfr = *(const short8*)(&Bs[n4 * 16 + lr][kc * 32 + quad * 8]);
                acc[n4] = __builtin_amdgcn_mfma_f32_16x16x32_bf16(bfr, af[kc].s, acc[n4], 0, 0, 0);
            }
        }
        if (ct < 2) {
            unsigned short* dst = qb + (size_t)row * 128 + ct * 64;
            #pragma unroll
            for (int n4 = 0; n4 < 4; ++n4) {
                int colb = n4 * 16 + quad * 4;
                float4 bv = *(const float4*)(bias + ct * 64 + colb);
                ushort4 o;
                o.x = f2h(acc[n4][0] + bv.x);
                o.y = f2h(acc[n4][1] + bv.y);
                o.z = f2h(acc[n4][2] + bv.z);
                o.w = f2h(acc[n4][3] + bv.w);
                *(ushort4*)(dst + colb) = o;
            }
        } else {
            unsigned char* dst = kvb + (size_t)row * 256 + (ct - 2) * 64;
            #pragma unroll
            for (int n4 = 0; n4 < 4; ++n4) {
                int colb = n4 * 16 + quad * 4;
                float4 bv = *(const float4*)(bias + ct * 64 + colb);
                *(unsigned int*)(dst + colb) = f32x4_to_fp8(
                    acc[n4][0] + bv.x, acc[n4][1] + bv.y,
                    acc[n4][2] + bv.z, acc[n4][3] + bv.w);
            }
        }
        __syncthreads();               // all Bs reads done
        if (ct < 5) {
            #pragma unroll
            for (int i = 0; i < 4; ++i)
                *(u16x8*)(&Bs[sr + i * 16][sc8]) = stg[i];
            __syncthreads();           // Bs ct+1 ready
        }
    }
}

// Fused: out-GEMM (gelu(agg)@aWT + skip -> h) then second GEMM from h (in LDS).
// T14 staging throughout.
template <int HPFMT, int P2>
__global__ __launch_bounds__(256) void fused_kernel(
    const unsigned short* __restrict__ aggb,
    const unsigned short* __restrict__ aWT, const float* __restrict__ ab,
    const float* __restrict__ skip_p,
    const float* __restrict__ HprevF, const unsigned short* __restrict__ HprevB,
    unsigned short* __restrict__ hb_out,
    const unsigned short* __restrict__ W2T, const float* __restrict__ bias2,
    unsigned short* __restrict__ qb, unsigned char* __restrict__ kvb,
    float* __restrict__ outF)
{
    __shared__ unsigned short As[64][136];
    __shared__ unsigned short Bs[64][136];
    int t = threadIdx.x;
    int row0 = blockIdx.x * 64;
    int w = t >> 6;
    int lr = t & 15;
    int quad = (t & 63) >> 4;
    int row = row0 + w * 16 + lr;
    int sr = t >> 4;
    int sc8 = (t & 15) * 8;

    frag8 agf[4];
    {
        const unsigned short* ap = aggb + (size_t)row * 128 + quad * 8;
        #pragma unroll
        for (int kc = 0; kc < 4; ++kc) {
            u16x8 u = *(const u16x8*)(ap + kc * 32);
            #pragma unroll
            for (int j = 0; j < 8; ++j) agf[kc].u[j] = f2bf(gelu_tanh(bf2f(u[j])));
        }
    }

    float sv = skip_p[0];
    float beta = 1.f / (1.f + expf(-sv));
    float omb = 1.f - beta;

    u16x8 stg[4];
    // prologue: stage aWT ct=0
    #pragma unroll
    for (int i = 0; i < 4; ++i)
        stg[i] = *(const u16x8*)(aWT + (size_t)(sr + i * 16) * 128 + sc8);
    #pragma unroll
    for (int i = 0; i < 4; ++i)
        *(u16x8*)(&Bs[sr + i * 16][sc8]) = stg[i];
    __syncthreads();

    f32x4 hacc[2][4];
    // ---- phase B ct=0 ----
    #pragma unroll
    for (int i = 0; i < 4; ++i)   // issue aWT ct=1 loads
        stg[i] = *(const u16x8*)(aWT + (size_t)(64 + sr + i * 16) * 128 + sc8);
    #pragma unroll
    for (int n4 = 0; n4 < 4; ++n4) hacc[0][n4] = (f32x4){0.f,0.f,0.f,0.f};
    #pragma unroll
    for (int kc = 0; kc < 4; ++kc) {
        #pragma unroll
        for (int n4 = 0; n4 < 4; ++n4) {
            short8 bfr = *(const short8*)(&Bs[n4 * 16 + lr][kc * 32 + quad * 8]);
            hacc[0][n4] = __builtin_amdgcn_mfma_f32_16x16x32_bf16(bfr, agf[kc].s, hacc[0][n4], 0, 0, 0);
        }
    }
    __syncthreads();
    #pragma unroll
    for (int i = 0; i < 4; ++i)
        *(u16x8*)(&Bs[sr + i * 16][sc8]) = stg[i];
    __syncthreads();
    // ---- phase B ct=1 (issue W2T tile-0 loads during compute) ----
    #pragma unroll
    for (int i = 0; i < 4; ++i)
        stg[i] = *(const u16x8*)(W2T + (size_t)(sr + i * 16) * 128 + sc8);
    #pragma unroll
    for (int n4 = 0; n4 < 4; ++n4) hacc[1][n4] = (f32x4){0.f,0.f,0.f,0.f};
    #pragma unroll
    for (int kc = 0; kc < 4; ++kc) {
        #pragma unroll
        for (int n4 = 0; n4 < 4; ++n4) {
            short8 bfr = *(const short8*)(&Bs[n4 * 16 + lr][kc * 32 + quad * 8]);
            hacc[1][n4] = __builtin_amdgcn_mfma_f32_16x16x32_bf16(bfr, agf[kc].s, hacc[1][n4], 0, 0, 0);
        }
    }

    // ---- h = relu(beta*(out+ab) + (1-beta)*hprev) -> As (+hb for P2==0) ----
    #pragma unroll
    for (int ct = 0; ct < 2; ++ct) {
        #pragma unroll
        for (int n4 = 0; n4 < 4; ++n4) {
            int colb = ct * 64 + n4 * 16 + quad * 4;
            float4 bv = *(const float4*)(ab + colb);
            float hp[4];
            if (HPFMT == 0) {
                float4 h4 = *(const float4*)(HprevF + (size_t)row * 128 + colb);
                hp[0] = h4.x; hp[1] = h4.y; hp[2] = h4.z; hp[3] = h4.w;
            } else {
                ushort4 h4 = *(const ushort4*)(HprevB + (size_t)row * 128 + colb);
                hp[0] = bf2f(h4.x); hp[1] = bf2f(h4.y); hp[2] = bf2f(h4.z); hp[3] = bf2f(h4.w);
            }
            ushort4 o;
            o.x = f2bf(fmaxf(beta * (hacc[ct][n4][0] + bv.x) + omb * hp[0], 0.f));
            o.y = f2bf(fmaxf(beta * (hacc[ct][n4][1] + bv.y) + omb * hp[1], 0.f));
            o.z = f2bf(fmaxf(beta * (hacc[ct][n4][2] + bv.z) + omb * hp[2], 0.f));
            o.w = f2bf(fmaxf(beta * (hacc[ct][n4][3] + bv.w) + omb * hp[3], 0.f));
            *(ushort4*)(&As[w * 16 + lr][colb]) = o;
            if (P2 == 0) *(ushort4*)(hb_out + (size_t)row * 128 + colb) = o;
        }
    }
    __syncthreads();                   // phase-B Bs reads done everywhere
    #pragma unroll
    for (int i = 0; i < 4; ++i)        // Bs <- W2T tile 0 (loads long since issued)
        *(u16x8*)(&Bs[sr + i * 16][sc8]) = stg[i];
    __syncthreads();

    // ---------- phase C: h @ W2T ----------
    if (P2 == 0) {
        #pragma unroll
        for (int ct = 0; ct < 6; ++ct) {
            if (ct < 5) {
                #pragma unroll
                for (int i = 0; i < 4; ++i)
                    stg[i] = *(const u16x8*)(W2T + (size_t)((ct + 1) * 64 + sr + i * 16) * 128 + sc8);
            }
            f32x4 acc[4] = {{0.f,0.f,0.f,0.f},{0.f,0.f,0.f,0.f},
                            {0.f,0.f,0.f,0.f},{0.f,0.f,0.f,0.f}};
            #pragma unroll
            for (int kc = 0; kc < 4; ++kc) {
                short8 afr = *(const short8*)(&As[w * 16 + lr][kc * 32 + quad * 8]);
                #pragma unroll
                for (int n4 = 0; n4 < 4; ++n4) {
                    short8 bfr = *(const short8*)(&Bs[n4 * 16 + lr][kc * 32 + quad * 8]);
                    acc[n4] = __builtin_amdgcn_mfma_f32_16x16x32_bf16(bfr, afr, acc[n4], 0, 0, 0);
                }
            }
            if (ct < 2) {
                unsigned short* dst = qb + (size_t)row * 128 + ct * 64;
                #pragma unroll
                for (int n4 = 0; n4 < 4; ++n4) {
                    int colb = n4 * 16 + quad * 4;
                    float4 bv = *(const float4*)(bias2 + ct * 64 + colb);
                    ushort4 o;
                    o.x = f2h(acc[n4][0] + bv.x);
                    o.y = f2h(acc[n4][1] + bv.y);
                    o.z = f2h(acc[n4][2] + bv.z);
                    o.w = f2h(acc[n4][3] + bv.w);
                    *(ushort4*)(dst + colb) = o;
                }
            } else {
                unsigned char* dst = kvb + (size_t)row * 256 + (ct - 2) * 64;
                #pragma unroll
                for (int n4 = 0; n4 < 4; ++n4) {
                    int colb = n4 * 16 + quad * 4;
                    float4 bv = *(const float4*)(bias2 + ct * 64 + colb);
                    *(unsigned int*)(dst + colb) = f32x4_to_fp8(
                        acc[n4][0] + bv.x, acc[n4][1] + bv.y,
                        acc[n4][2] + bv.z, acc[n4][3] + bv.w);
                }
            }
            __syncthreads();
            if (ct < 5) {
                #pragma unroll
                for (int i = 0; i < 4; ++i)
                    *(u16x8*)(&Bs[sr + i * 16][sc8]) = stg[i];
                __syncthreads();
            }
        }
    } else {
        f32x4 acc[4] = {{0.f,0.f,0.f,0.f},{0.f,0.f,0.f,0.f},
                        {0.f,0.f,0.f,0.f},{0.f,0.f,0.f,0.f}};
        #pragma unroll
        for (int kc = 0; kc < 4; ++kc) {
            short8 afr = *(const short8*)(&As[w * 16 + lr][kc * 32 + quad * 8]);
            #pragma unroll
            for (int n4 = 0; n4 < 4; ++n4) {
                short8 bfr = *(const short8*)(&Bs[n4 * 16 + lr][kc * 32 + quad * 8]);
                acc[n4] = __builtin_amdgcn_mfma_f32_16x16x32_bf16(bfr, afr, acc[n4], 0, 0, 0);
            }
        }
        #pragma unroll
        for (int n4 = 0; n4 < 4; ++n4) {
            int colb = n4 * 16 + quad * 4;
            float4 bv = *(const float4*)(bias2 + colb);
            float4 o;
            o.x = acc[n4][0] + bv.x;
            o.y = acc[n4][1] + bv.y;
            o.z = acc[n4][2] + bv.z;
            o.w = acc[n4][3] + bv.w;
            *(float4*)(outF + (size_t)row * 64 + colb) = o;
        }
    }
}

// ---------------- Fused per-destination softmax + aggregation --------------------
// Lane map: 64 lanes = 4 edge-slots (es) x 8 heads (h) x 2 dim-halves (half).
// Each lane: 8 dims of one head for one edge. Full QK dot via shfl_xor(.,1).
// Reduction: den over masks {1,16,32}; acc[8] over {16,32} (19 shuffles vs 51).
// Per edge-row, 16 lanes read a contiguous 128 B (K) / 128 B (V) -> 2 lines each.
__global__ __launch_bounds__(256) void aggregate_kernel(
    const unsigned short* __restrict__ qb, const unsigned char* __restrict__ kvb,
    const int* __restrict__ podeg,
    const int* __restrict__ srcSorted, unsigned short* __restrict__ aggb)
{
    int n = (blockIdx.x * 256 + threadIdx.x) >> 6;
    int lane = threadIdx.x & 63;
    int half = lane & 1;
    int h = (lane >> 1) & 7;
    int es = lane >> 4;                 // 0..3
    int qoff = h * 16 + half * 8;       // shorts into qb/aggb; bytes into kvb (1B/dim)

    float qf[8];
    {
        kv8 a;
        a.u = *(const u16x8*)(qb + (size_t)n * 128 + qoff);
        #pragma unroll
        for (int j = 0; j < 8; ++j) qf[j] = (float)a.h[j];
    }
    float acc[8];
    #pragma unroll
    for (int j = 0; j < 8; ++j) acc[j] = 0.f;
    float den = 0.f;

    int pd = podeg[n];
    int start = pd & 0xFFFFF;
    int d = ((unsigned)pd) >> 20;
    if (d > 0) {
        int ng = (d + 3) >> 2;
        int lastIdx = start + d - 1;

        int2 kA, vA, kB, vB;
        {
            int i0 = start + es; if (i0 > lastIdx) i0 = lastIdx;
            const unsigned char* p = kvb + (size_t)srcSorted[i0] * 256 + qoff;
            kA = *(const int2*)p;
            vA = *(const int2*)(p + 128);
        }
        kB = kA; vB = vA;
        if (ng > 1) {
            int i1 = start + 4 + es; if (i1 > lastIdx) i1 = lastIdx;
            const unsigned char* p = kvb + (size_t)srcSorted[i1] * 256 + qoff;
            kB = *(const int2*)p;
            vB = *(const int2*)(p + 128);
        }

        for (int g = 0; g < ng; ++g) {
            int2 kC = kA, vC = vA;
            if (g + 2 < ng) {
                int ni = start + (g + 2) * 4 + es; if (ni > lastIdx) ni = lastIdx;
                const unsigned char* p = kvb + (size_t)srcSorted[ni] * 256 + qoff;
                kC = *(const int2*)p;
                vC = *(const int2*)(p + 128);
            }
            float pdot = 0.f;
            {
                float kf[8];
                fp8x4_to_f32((unsigned int)kA.x, kf);
                fp8x4_to_f32((unsigned int)kA.y, kf + 4);
                #pragma unroll
                for (int j = 0; j < 8; ++j) pdot = fmaf(kf[j], qf[j], pdot);
            }
            pdot += __shfl_xor(pdot, 1, 64);          // combine dim-halves
            float ev = (g * 4 + es < d) ? fast_exp2(pdot) : 0.f;
            den += half ? 0.f : ev;                   // count each edge once
            {
                float vf[8];
                fp8x4_to_f32((unsigned int)vA.x, vf);
                fp8x4_to_f32((unsigned int)vA.y, vf + 4);
                #pragma unroll
                for (int j = 0; j < 8; ++j) acc[j] = fmaf(vf[j], ev, acc[j]);
            }
            kA = kB; vA = vB;
            kB = kC; vB = vC;
        }
    }
    den += __shfl_xor(den, 1, 64);                    // across halves
    #pragma unroll
    for (int m = 16; m < 64; m <<= 1) {               // across edge-slots
        den += __shfl_xor(den, m, 64);
        #pragma unroll
        for (int j = 0; j < 8; ++j) acc[j] += __shfl_xor(acc[j], m, 64);
    }
    if (es == 0) {
        float w = 1.f / (den + 1e-16f);
        u16x8 o;
        #pragma unroll
        for (int j = 0; j < 8; ++j) o[j] = f2bf(acc[j] * w);
        *(u16x8*)(aggb + (size_t)n * 128 + qoff) = o;
    }
}

extern "C" void kernel_launch(void* const* d_in, const int* in_sizes, int n_in,
                              void* d_out, int out_size, void* d_ws, size_t ws_size,
                              hipStream_t stream) {
    const float* x     = (const float*)d_in[0];
    const int*   eidx  = (const int*)d_in[1];
    const float* Wk    = (const float*)d_in[2];
    const float* bk    = (const float*)d_in[3];
    const float* Wq    = (const float*)d_in[4];
    const float* bq    = (const float*)d_in[5];
    const float* Wv    = (const float*)d_in[6];
    const float* bv    = (const float*)d_in[7];
    const float* a_rel = (const float*)d_in[8];
    const float* m_rel = (const float*)d_in[9];
    const float* p_rel = (const float*)d_in[10];
    const float* skip  = (const float*)d_in[11];
    const float* aW    = (const float*)d_in[12];
    const float* ab    = (const float*)d_in[13];
    const float* fcW   = (const float*)d_in[14];
    const float* fcb   = (const float*)d_in[15];
    float* out = (float*)d_out;

    float* biasf = (float*)d_ws;                              // 2*384
    unsigned short* hb   = (unsigned short*)(biasf + 768);    // NN*128 bf16
    unsigned short* qb   = hb + (size_t)NN * 128;             // NN*128 f16
    unsigned char*  kvb  = (unsigned char*)(qb + (size_t)NN * 128); // NN*256 B fp8
    unsigned short* aggb = (unsigned short*)(kvb + (size_t)NN * 256); // NN*128 bf16
    unsigned short* BfT  = aggb + (size_t)NN * 128;           // 2*384*128
    unsigned short* aWT  = BfT + 2 * 384 * 128;               // 2*128*128
    unsigned short* fcWT = aWT + 2 * 128 * 128;               // 64*128
    int* podeg     = (int*)(fcWT + 64 * 128);                 // NN (offs | deg<<20)
    int* gcur      = podeg + NN;                              // NCO (pad 160)
    int* ebuk      = gcur + 160;                              // NCO*BCAP
    int* srcSorted = ebuk + NCO * BCAP;                       // NCO*BCAP

    // zero the coarse-bucket cursors (captured as a graph memset node)
    hipMemsetAsync(gcur, 0, NCO * sizeof(int), stream);

    // weights + coarse scatter (one dispatch, disjoint block ranges)
    prep_kernel<<<P1B + WBLOCKS, 256, 0, stream>>>(
        Wq, bq, Wk, bk, a_rel, Wv, bv, m_rel, p_rel, aW, fcW,
        BfT, biasf, aWT, fcWT, eidx, gcur, ebuk);

    // layer-0 QKV GEMM + CSR pass 3 (co-scheduled)
    qkv0_p3_kernel<<<GBLOCKS + NCO, 256, 0, stream>>>(
        x, BfT, biasf, qb, kvb, gcur, ebuk, podeg, srcSorted);

    aggregate_kernel<<<NN / 4, 256, 0, stream>>>(qb, kvb, podeg, srcSorted, aggb);

    // out-GEMM(L0) -> h0 -> QKV(L1) (qb/kvb overwritten in place; agg L0 done)
    fused_kernel<0, 0><<<GBLOCKS, 256, 0, stream>>>(
        aggb, aWT, ab, skip, x, nullptr, hb,
        BfT + 49152, biasf + 384, qb, kvb, nullptr);

    aggregate_kernel<<<NN / 4, 256, 0, stream>>>(qb, kvb, podeg, srcSorted, aggb);

    // out-GEMM(L1) -> h1 (LDS) -> fc -> out
    fused_kernel<1, 2><<<GBLOCKS, 256, 0, stream>>>(
        aggb, aWT + 16384, ab + 128, skip + 1, nullptr, hb, nullptr,
        fcWT, fcb, nullptr, nullptr, out);
}

// Round 8
// 224.746 us; speedup vs baseline: 1.2284x; 1.0589x over previous
//
#include <hip/hip_runtime.h>
#include <hip/hip_bf16.h>
#include <math.h>

#define NN 40000
#define NE 640000

typedef __attribute__((ext_vector_type(8))) short short8;
typedef __attribute__((ext_vector_type(8))) unsigned short u16x8;
typedef __attribute__((ext_vector_type(4))) float f32x4;
typedef __attribute__((ext_vector_type(2))) float f32v2;
typedef _Float16 h16x2 __attribute__((ext_vector_type(2)));

#define WBLOCKS 547   // weight-prep blocks
#define GBLOCKS 625   // GEMM row blocks (NN/64)
#define NCO 157       // coarse buckets (dst>>8)
#define P1B 160       // scatter blocks
#define EPB 4000      // edges per scatter block (NE/P1B)
#define BCAP 5120     // padded capacity per coarse bucket (16 sigma margin)

#if __has_builtin(__builtin_amdgcn_cvt_pk_f32_fp8) && __has_builtin(__builtin_amdgcn_cvt_pk_fp8_f32)
#define HAS_FP8CVT 1
#else
#define HAS_FP8CVT 0
#endif

__device__ __forceinline__ float fast_exp2(float x) {
#if __has_builtin(__builtin_amdgcn_exp2f)
    return __builtin_amdgcn_exp2f(x);
#else
    return exp2f(x);
#endif
}

// tanh-gelu, mathematically identical to 0.5x(1+tanh(u)) via tanh(u)=1-2/(1+e^{2u})
__device__ __forceinline__ float gelu_tanh(float x) {
    float x3 = x * x * x;
    float u = 0.7978845608028654f * (x + 0.044715f * x3);
    float t = 1.0f - 2.0f / (1.0f + fast_exp2(2.885390081777927f * u));
    return 0.5f * x * (1.0f + t);
}

__device__ __forceinline__ unsigned short f2bf(float v) {
    __hip_bfloat16 h = __float2bfloat16(v);
    return *reinterpret_cast<unsigned short*>(&h);
}

__device__ __forceinline__ unsigned short f2h(float v) {
    union { _Float16 h; unsigned short u; } c;
    c.h = (_Float16)v;
    return c.u;
}

__device__ __forceinline__ float bf2f(unsigned short u) {
    union { unsigned int i; float f; } c;
    c.i = ((unsigned int)u) << 16;
    return c.f;
}

// ---------------- fp8 e4m3 pack/unpack --------------------------------------
#if HAS_FP8CVT
__device__ __forceinline__ unsigned int f32x4_to_fp8(float a, float b, float c, float d) {
    int r = 0;
    r = __builtin_amdgcn_cvt_pk_fp8_f32(a, b, r, false);
    r = __builtin_amdgcn_cvt_pk_fp8_f32(c, d, r, true);
    return (unsigned int)r;
}
__device__ __forceinline__ void fp8x4_to_f32(unsigned int w, float* o) {
    f32v2 lo = __builtin_amdgcn_cvt_pk_f32_fp8((int)w, false);
    f32v2 hi = __builtin_amdgcn_cvt_pk_f32_fp8((int)w, true);
    o[0] = lo[0]; o[1] = lo[1]; o[2] = hi[0]; o[3] = hi[1];
}
#else
__device__ __forceinline__ unsigned char f2fp8_sw(float x) {
    union { float f; unsigned u; } c; c.f = x;
    unsigned sgn = (c.u >> 31) << 7;
    c.u &= 0x7fffffffu;
    if (!(c.f < 464.f)) return (unsigned char)(sgn | 0x7e);
    if (c.f < 0.0009765625f) return (unsigned char)sgn;
    if (c.f < 0.015625f) {
        int q = (int)rintf(c.f * 512.f);
        if (q > 7) return (unsigned char)(sgn | 0x08);
        return (unsigned char)(sgn | q);
    }
    unsigned u = c.u;
    unsigned lsb = (u >> 20) & 1;
    u += 0x7ffffu + lsb;
    int e8 = (int)(u >> 23) - 127 + 7;
    if (e8 > 15) return (unsigned char)(sgn | 0x7e);
    unsigned m = (u >> 20) & 7;
    return (unsigned char)(sgn | (e8 << 3) | m);
}
__device__ __forceinline__ float fp8_to_f32_sw(unsigned char b) {
    int e = (b >> 3) & 15, m = b & 7;
    float v = (e == 0) ? ldexpf((float)m, -9) : ldexpf(8.0f + (float)m, e - 10);
    return (b & 0x80) ? -v : v;
}
__device__ __forceinline__ unsigned int f32x4_to_fp8(float a, float b, float c, float d) {
    return (unsigned int)f2fp8_sw(a) | ((unsigned int)f2fp8_sw(b) << 8) |
           ((unsigned int)f2fp8_sw(c) << 16) | ((unsigned int)f2fp8_sw(d) << 24);
}
__device__ __forceinline__ void fp8x4_to_f32(unsigned int w, float* o) {
    o[0] = fp8_to_f32_sw((unsigned char)(w & 0xff));
    o[1] = fp8_to_f32_sw((unsigned char)((w >> 8) & 0xff));
    o[2] = fp8_to_f32_sw((unsigned char)((w >> 16) & 0xff));
    o[3] = fp8_to_f32_sw((unsigned char)((w >> 24) & 0xff));
}
#endif

union kv8 { u16x8 u; h16x2 p[4]; _Float16 h[8]; };
union frag8 { short8 s; unsigned short u[8]; u16x8 v; };

// ---- merged: coarse scatter w/ atomic range reservation (blocks 0..P1B-1) ----
// ---- + weight prep (blocks P1B..P1B+WBLOCKS-1) --------------------------------
__global__ __launch_bounds__(256) void prep_kernel(
    const float* __restrict__ Wq, const float* __restrict__ bq,
    const float* __restrict__ Wk, const float* __restrict__ bk,
    const float* __restrict__ a_rel,
    const float* __restrict__ Wv, const float* __restrict__ bv,
    const float* __restrict__ m_rel,
    const float* __restrict__ p_rel,
    const float* __restrict__ aW, const float* __restrict__ fcW,
    unsigned short* __restrict__ BfT, float* __restrict__ biasf,
    unsigned short* __restrict__ aWT, unsigned short* __restrict__ fcWT,
    const int* __restrict__ eidx, int* __restrict__ gcur, int* __restrict__ ebuk)
{
    if (blockIdx.x < P1B) {
        __shared__ int cnt[NCO];
        __shared__ int cur[NCO];
        int b = blockIdx.x;
        int t = threadIdx.x;
        if (t < NCO) cnt[t] = 0;
        __syncthreads();
        int bs = b * EPB;
        for (int e = bs + t; e < bs + EPB; e += 256)
            atomicAdd(&cnt[eidx[NE + e] >> 8], 1);
        __syncthreads();
        if (t < NCO) cur[t] = atomicAdd(&gcur[t], cnt[t]);
        __syncthreads();
        for (int e = bs + t; e < bs + EPB; e += 256) {
            int s = eidx[e];
            int d = eidx[NE + e];
            int cb = d >> 8;
            int pos = atomicAdd(&cur[cb], 1);
            ebuk[cb * BCAP + pos] = ((d & 255) << 16) | s;
        }
        return;
    }
    int idx = (blockIdx.x - P1B) * 256 + threadIdx.x;
    if (idx < 2 * 129 * 384) {
        int l = idx / (129 * 384);
        int j = idx - l * (129 * 384);
        int r = j / 384;
        int col = j - r * 384;
        const float* Wq_l = Wq + l * 16384;
        const float* Wk_l = Wk + l * 16384;
        const float* Wv_l = Wv + l * 16384;
        const float* ar_l = a_rel + l * 2048;
        const float* mr_l = m_rel + l * 2048;
        float val;
        if (col < 128) {
            val = (r < 128) ? Wq_l[r * 128 + col] : bq[l * 128 + col];
        } else if (col < 256) {
            int cc = col - 128; int h = cc >> 4; int eo = cc & 15;
            float scale = p_rel[l * 8 + h] * 0.25f * 1.4426950408889634f;
            float s = 0.f;
            #pragma unroll
            for (int d = 0; d < 16; ++d) {
                float w = (r < 128) ? Wk_l[r * 128 + h * 16 + d] : bk[l * 128 + h * 16 + d];
                s += w * ar_l[h * 256 + d * 16 + eo];
            }
            val = s * scale;
        } else {
            int cc = col - 256; int h = cc >> 4; int eo = cc & 15;
            float s = 0.f;
            #pragma unroll
            for (int d = 0; d < 16; ++d) {
                float w = (r < 128) ? Wv_l[r * 128 + h * 16 + d] : bv[l * 128 + h * 16 + d];
                s += w * mr_l[h * 256 + d * 16 + eo];
            }
            val = s;
        }
        if (r < 128) BfT[(size_t)l * 49152 + (size_t)col * 128 + r] = f2bf(val);
        else         biasf[l * 384 + col] = val;
    } else if (idx < 2 * 129 * 384 + 2 * 16384) {
        int i = idx - 2 * 129 * 384;
        int l = i >> 14; int j = i & 16383;
        int r = j >> 7, c = j & 127;
        aWT[(size_t)l * 16384 + (size_t)c * 128 + r] = f2bf(aW[(size_t)l * 16384 + r * 128 + c]);
    } else {
        int i = idx - (2 * 129 * 384 + 2 * 16384);
        int c = i >> 7, r = i & 127;
        fcWT[(size_t)c * 128 + r] = f2bf(fcW[(size_t)r * 64 + c]);
    }
}

// ---- qkv0 GEMM (blocks 0..624) + CSR pass 3 (blocks 625..781) -------------------
// qb rows: f16 [NN][128].  kvb rows: [k fp8 (128 B) | v fp8 (128 B)], 256 B.
// B-tile staging uses T14 issue-early/write-late (regs -> LDS after compute).
__global__ __launch_bounds__(256) void qkv0_p3_kernel(
    const float* __restrict__ Af, const unsigned short* __restrict__ BT,
    const float* __restrict__ bias,
    unsigned short* __restrict__ qb, unsigned char* __restrict__ kvb,
    const int* __restrict__ gcnt, const int* __restrict__ ebuk,
    int* __restrict__ podeg, int* __restrict__ srcSorted)
{
    if (blockIdx.x >= GBLOCKS) {
        // pass 3: fine grouping within one coarse bucket, LDS only
        __shared__ int hist[256], loffs[256], cur[256];
        int c = blockIdx.x - GBLOCKS;
        int t = threadIdx.x;
        int base = c * BCAP;
        int end = base + gcnt[c];
        hist[t] = 0;
        __syncthreads();
        for (int i = base + t; i < end; i += 256)
            atomicAdd(&hist[ebuk[i] >> 16], 1);
        __syncthreads();
        int v = hist[t];
        loffs[t] = v;
        __syncthreads();
        #pragma unroll
        for (int off = 1; off < 256; off <<= 1) {
            int u = (t >= off) ? loffs[t - off] : 0;
            __syncthreads();
            loffs[t] += u;
            __syncthreads();
        }
        int excl = loffs[t] - v;
        int n = c * 256 + t;
        if (n < NN) podeg[n] = (base + excl) | (v << 20);
        cur[t] = excl;
        __syncthreads();
        for (int i = base + t; i < end; i += 256) {
            int p = ebuk[i];
            int pos = atomicAdd(&cur[p >> 16], 1);
            srcSorted[base + pos] = p & 0xffff;
        }
        return;
    }
    __shared__ unsigned short Bs[64][136];
    int t = threadIdx.x;
    int row0 = blockIdx.x * 64;
    int w = t >> 6;
    int lr = t & 15;
    int quad = (t & 63) >> 4;
    int row = row0 + w * 16 + lr;
    int sr = t >> 4;
    int sc8 = (t & 15) * 8;

    frag8 af[4];
    {
        const float* ap = Af + (size_t)row * 128 + quad * 8;
        #pragma unroll
        for (int kc = 0; kc < 4; ++kc) {
            float4 a0 = *(const float4*)(ap + kc * 32);
            float4 a1 = *(const float4*)(ap + kc * 32 + 4);
            af[kc].u[0] = f2bf(a0.x); af[kc].u[1] = f2bf(a0.y);
            af[kc].u[2] = f2bf(a0.z); af[kc].u[3] = f2bf(a0.w);
            af[kc].u[4] = f2bf(a1.x); af[kc].u[5] = f2bf(a1.y);
            af[kc].u[6] = f2bf(a1.z); af[kc].u[7] = f2bf(a1.w);
        }
    }

    u16x8 stg[4];
    // prologue: stage ct=0
    #pragma unroll
    for (int i = 0; i < 4; ++i)
        stg[i] = *(const u16x8*)(BT + (size_t)(sr + i * 16) * 128 + sc8);
    #pragma unroll
    for (int i = 0; i < 4; ++i)
        *(u16x8*)(&Bs[sr + i * 16][sc8]) = stg[i];
    __syncthreads();

    #pragma unroll
    for (int ct = 0; ct < 6; ++ct) {
        // issue next tile's loads before compute (T14)
        if (ct < 5) {
            #pragma unroll
            for (int i = 0; i < 4; ++i)
                stg[i] = *(const u16x8*)(BT + (size_t)((ct + 1) * 64 + sr + i * 16) * 128 + sc8);
        }
        f32x4 acc[4] = {{0.f,0.f,0.f,0.f},{0.f,0.f,0.f,0.f},
                        {0.f,0.f,0.f,0.f},{0.f,0.f,0.f,0.f}};
        #pragma unroll
        for (int kc = 0; kc < 4; ++kc) {
            #pragma unroll
            for (int n4 = 0; n4 < 4; ++n4) {
                short8 bfr = *(const short8*)(&Bs[n4 * 16 + lr][kc * 32 + quad * 8]);
                acc[n4] = __builtin_amdgcn_mfma_f32_16x16x32_bf16(bfr, af[kc].s, acc[n4], 0, 0, 0);
            }
        }
        if (ct < 2) {
            unsigned short* dst = qb + (size_t)row * 128 + ct * 64;
            #pragma unroll
            for (int n4 = 0; n4 < 4; ++n4) {
                int colb = n4 * 16 + quad * 4;
                float4 bv = *(const float4*)(bias + ct * 64 + colb);
                ushort4 o;
                o.x = f2h(acc[n4][0] + bv.x);
                o.y = f2h(acc[n4][1] + bv.y);
                o.z = f2h(acc[n4][2] + bv.z);
                o.w = f2h(acc[n4][3] + bv.w);
                *(ushort4*)(dst + colb) = o;
            }
        } else {
            unsigned char* dst = kvb + (size_t)row * 256 + (ct - 2) * 64;
            #pragma unroll
            for (int n4 = 0; n4 < 4; ++n4) {
                int colb = n4 * 16 + quad * 4;
                float4 bv = *(const float4*)(bias + ct * 64 + colb);
                *(unsigned int*)(dst + colb) = f32x4_to_fp8(
                    acc[n4][0] + bv.x, acc[n4][1] + bv.y,
                    acc[n4][2] + bv.z, acc[n4][3] + bv.w);
            }
        }
        __syncthreads();               // all Bs reads done
        if (ct < 5) {
            #pragma unroll
            for (int i = 0; i < 4; ++i)
                *(u16x8*)(&Bs[sr + i * 16][sc8]) = stg[i];
            __syncthreads();           // Bs ct+1 ready
        }
    }
}

// Fused: out-GEMM (gelu(agg)@aWT + skip -> h) then second GEMM from h (in LDS).
// T14 staging throughout.
template <int HPFMT, int P2>
__global__ __launch_bounds__(256) void fused_kernel(
    const unsigned short* __restrict__ aggb,
    const unsigned short* __restrict__ aWT, const float* __restrict__ ab,
    const float* __restrict__ skip_p,
    const float* __restrict__ HprevF, const unsigned short* __restrict__ HprevB,
    unsigned short* __restrict__ hb_out,
    const unsigned short* __restrict__ W2T, const float* __restrict__ bias2,
    unsigned short* __restrict__ qb, unsigned char* __restrict__ kvb,
    float* __restrict__ outF)
{
    __shared__ unsigned short As[64][136];
    __shared__ unsigned short Bs[64][136];
    int t = threadIdx.x;
    int row0 = blockIdx.x * 64;
    int w = t >> 6;
    int lr = t & 15;
    int quad = (t & 63) >> 4;
    int row = row0 + w * 16 + lr;
    int sr = t >> 4;
    int sc8 = (t & 15) * 8;

    frag8 agf[4];
    {
        const unsigned short* ap = aggb + (size_t)row * 128 + quad * 8;
        #pragma unroll
        for (int kc = 0; kc < 4; ++kc) {
            u16x8 u = *(const u16x8*)(ap + kc * 32);
            #pragma unroll
            for (int j = 0; j < 8; ++j) agf[kc].u[j] = f2bf(gelu_tanh(bf2f(u[j])));
        }
    }

    float sv = skip_p[0];
    float beta = 1.f / (1.f + expf(-sv));
    float omb = 1.f - beta;

    u16x8 stg[4];
    // prologue: stage aWT ct=0
    #pragma unroll
    for (int i = 0; i < 4; ++i)
        stg[i] = *(const u16x8*)(aWT + (size_t)(sr + i * 16) * 128 + sc8);
    #pragma unroll
    for (int i = 0; i < 4; ++i)
        *(u16x8*)(&Bs[sr + i * 16][sc8]) = stg[i];
    __syncthreads();

    f32x4 hacc[2][4];
    // ---- phase B ct=0 ----
    #pragma unroll
    for (int i = 0; i < 4; ++i)   // issue aWT ct=1 loads
        stg[i] = *(const u16x8*)(aWT + (size_t)(64 + sr + i * 16) * 128 + sc8);
    #pragma unroll
    for (int n4 = 0; n4 < 4; ++n4) hacc[0][n4] = (f32x4){0.f,0.f,0.f,0.f};
    #pragma unroll
    for (int kc = 0; kc < 4; ++kc) {
        #pragma unroll
        for (int n4 = 0; n4 < 4; ++n4) {
            short8 bfr = *(const short8*)(&Bs[n4 * 16 + lr][kc * 32 + quad * 8]);
            hacc[0][n4] = __builtin_amdgcn_mfma_f32_16x16x32_bf16(bfr, agf[kc].s, hacc[0][n4], 0, 0, 0);
        }
    }
    __syncthreads();
    #pragma unroll
    for (int i = 0; i < 4; ++i)
        *(u16x8*)(&Bs[sr + i * 16][sc8]) = stg[i];
    __syncthreads();
    // ---- phase B ct=1 (issue W2T tile-0 loads during compute) ----
    #pragma unroll
    for (int i = 0; i < 4; ++i)
        stg[i] = *(const u16x8*)(W2T + (size_t)(sr + i * 16) * 128 + sc8);
    #pragma unroll
    for (int n4 = 0; n4 < 4; ++n4) hacc[1][n4] = (f32x4){0.f,0.f,0.f,0.f};
    #pragma unroll
    for (int kc = 0; kc < 4; ++kc) {
        #pragma unroll
        for (int n4 = 0; n4 < 4; ++n4) {
            short8 bfr = *(const short8*)(&Bs[n4 * 16 + lr][kc * 32 + quad * 8]);
            hacc[1][n4] = __builtin_amdgcn_mfma_f32_16x16x32_bf16(bfr, agf[kc].s, hacc[1][n4], 0, 0, 0);
        }
    }

    // ---- h = relu(beta*(out+ab) + (1-beta)*hprev) -> As (+hb for P2==0) ----
    #pragma unroll
    for (int ct = 0; ct < 2; ++ct) {
        #pragma unroll
        for (int n4 = 0; n4 < 4; ++n4) {
            int colb = ct * 64 + n4 * 16 + quad * 4;
            float4 bv = *(const float4*)(ab + colb);
            float hp[4];
            if (HPFMT == 0) {
                float4 h4 = *(const float4*)(HprevF + (size_t)row * 128 + colb);
                hp[0] = h4.x; hp[1] = h4.y; hp[2] = h4.z; hp[3] = h4.w;
            } else {
                ushort4 h4 = *(const ushort4*)(HprevB + (size_t)row * 128 + colb);
                hp[0] = bf2f(h4.x); hp[1] = bf2f(h4.y); hp[2] = bf2f(h4.z); hp[3] = bf2f(h4.w);
            }
            ushort4 o;
            o.x = f2bf(fmaxf(beta * (hacc[ct][n4][0] + bv.x) + omb * hp[0], 0.f));
            o.y = f2bf(fmaxf(beta * (hacc[ct][n4][1] + bv.y) + omb * hp[1], 0.f));
            o.z = f2bf(fmaxf(beta * (hacc[ct][n4][2] + bv.z) + omb * hp[2], 0.f));
            o.w = f2bf(fmaxf(beta * (hacc[ct][n4][3] + bv.w) + omb * hp[3], 0.f));
            *(ushort4*)(&As[w * 16 + lr][colb]) = o;
            if (P2 == 0) *(ushort4*)(hb_out + (size_t)row * 128 + colb) = o;
        }
    }
    __syncthreads();                   // phase-B Bs reads done everywhere
    #pragma unroll
    for (int i = 0; i < 4; ++i)        // Bs <- W2T tile 0 (loads long since issued)
        *(u16x8*)(&Bs[sr + i * 16][sc8]) = stg[i];
    __syncthreads();

    // ---------- phase C: h @ W2T ----------
    if (P2 == 0) {
        #pragma unroll
        for (int ct = 0; ct < 6; ++ct) {
            if (ct < 5) {
                #pragma unroll
                for (int i = 0; i < 4; ++i)
                    stg[i] = *(const u16x8*)(W2T + (size_t)((ct + 1) * 64 + sr + i * 16) * 128 + sc8);
            }
            f32x4 acc[4] = {{0.f,0.f,0.f,0.f},{0.f,0.f,0.f,0.f},
                            {0.f,0.f,0.f,0.f},{0.f,0.f,0.f,0.f}};
            #pragma unroll
            for (int kc = 0; kc < 4; ++kc) {
                short8 afr = *(const short8*)(&As[w * 16 + lr][kc * 32 + quad * 8]);
                #pragma unroll
                for (int n4 = 0; n4 < 4; ++n4) {
                    short8 bfr = *(const short8*)(&Bs[n4 * 16 + lr][kc * 32 + quad * 8]);
                    acc[n4] = __builtin_amdgcn_mfma_f32_16x16x32_bf16(bfr, afr, acc[n4], 0, 0, 0);
                }
            }
            if (ct < 2) {
                unsigned short* dst = qb + (size_t)row * 128 + ct * 64;
                #pragma unroll
                for (int n4 = 0; n4 < 4; ++n4) {
                    int colb = n4 * 16 + quad * 4;
                    float4 bv = *(const float4*)(bias2 + ct * 64 + colb);
                    ushort4 o;
                    o.x = f2h(acc[n4][0] + bv.x);
                    o.y = f2h(acc[n4][1] + bv.y);
                    o.z = f2h(acc[n4][2] + bv.z);
                    o.w = f2h(acc[n4][3] + bv.w);
                    *(ushort4*)(dst + colb) = o;
                }
            } else {
                unsigned char* dst = kvb + (size_t)row * 256 + (ct - 2) * 64;
                #pragma unroll
                for (int n4 = 0; n4 < 4; ++n4) {
                    int colb = n4 * 16 + quad * 4;
                    float4 bv = *(const float4*)(bias2 + ct * 64 + colb);
                    *(unsigned int*)(dst + colb) = f32x4_to_fp8(
                        acc[n4][0] + bv.x, acc[n4][1] + bv.y,
                        acc[n4][2] + bv.z, acc[n4][3] + bv.w);
                }
            }
            __syncthreads();
            if (ct < 5) {
                #pragma unroll
                for (int i = 0; i < 4; ++i)
                    *(u16x8*)(&Bs[sr + i * 16][sc8]) = stg[i];
                __syncthreads();
            }
        }
    } else {
        f32x4 acc[4] = {{0.f,0.f,0.f,0.f},{0.f,0.f,0.f,0.f},
                        {0.f,0.f,0.f,0.f},{0.f,0.f,0.f,0.f}};
        #pragma unroll
        for (int kc = 0; kc < 4; ++kc) {
            short8 afr = *(const short8*)(&As[w * 16 + lr][kc * 32 + quad * 8]);
            #pragma unroll
            for (int n4 = 0; n4 < 4; ++n4) {
                short8 bfr = *(const short8*)(&Bs[n4 * 16 + lr][kc * 32 + quad * 8]);
                acc[n4] = __builtin_amdgcn_mfma_f32_16x16x32_bf16(bfr, afr, acc[n4], 0, 0, 0);
            }
        }
        #pragma unroll
        for (int n4 = 0; n4 < 4; ++n4) {
            int colb = n4 * 16 + quad * 4;
            float4 bv = *(const float4*)(bias2 + colb);
            float4 o;
            o.x = acc[n4][0] + bv.x;
            o.y = acc[n4][1] + bv.y;
            o.z = acc[n4][2] + bv.z;
            o.w = acc[n4][3] + bv.w;
            *(float4*)(outF + (size_t)row * 64 + colb) = o;
        }
    }
}

// ---------------- Fused per-destination softmax + aggregation --------------------
// Lane map: 64 lanes = 4 edge-slots (es) x 8 heads (h) x 2 dim-halves (half).
// Edge indices for the node are preloaded into registers (lane l holds
// srcSorted[start+min(l,d-1)]); per-group index comes from __shfl, removing the
// dependent index->kv load chain. k/v pipeline is 3-ahead (4 buffers).
__global__ __launch_bounds__(256) void aggregate_kernel(
    const unsigned short* __restrict__ qb, const unsigned char* __restrict__ kvb,
    const int* __restrict__ podeg,
    const int* __restrict__ srcSorted, unsigned short* __restrict__ aggb)
{
    int n = (blockIdx.x * 256 + threadIdx.x) >> 6;
    int lane = threadIdx.x & 63;
    int half = lane & 1;
    int h = (lane >> 1) & 7;
    int es = lane >> 4;                 // 0..3
    int qoff = h * 16 + half * 8;       // shorts into qb/aggb; bytes into kvb

    float qf[8];
    {
        kv8 a;
        a.u = *(const u16x8*)(qb + (size_t)n * 128 + qoff);
        #pragma unroll
        for (int j = 0; j < 8; ++j) qf[j] = (float)a.h[j];
    }
    float acc[8];
    #pragma unroll
    for (int j = 0; j < 8; ++j) acc[j] = 0.f;
    float den = 0.f;

    int pd = podeg[n];
    int start = pd & 0xFFFFF;
    int d = ((unsigned)pd) >> 20;
    if (d > 0) {
        int ng = (d + 3) >> 2;
        // preload clamped edge-index list into the wave (1 coalesced load)
        int clampLane = lane < (d - 1) ? lane : (d - 1);
        int myIdx = srcSorted[start + clampLane];

        auto fetch = [&](int g, int2& k, int2& v) {
            int pos = g * 4 + es;
            if (pos > d - 1) pos = d - 1;
            int src = (pos < 64) ? __shfl(myIdx, pos, 64)
                                 : srcSorted[start + pos];   // deg>64: ~never
            const unsigned char* p = kvb + (size_t)src * 256 + qoff;
            k = *(const int2*)p;
            v = *(const int2*)(p + 128);
        };

        int2 kA, vA, kB, vB, kC, vC;
        fetch(0, kA, vA);
        kB = kA; vB = vA; kC = kA; vC = vA;
        if (ng > 1) fetch(1, kB, vB);
        if (ng > 2) fetch(2, kC, vC);

        for (int g = 0; g < ng; ++g) {
            int2 kD = kA, vD = vA;
            if (g + 3 < ng) fetch(g + 3, kD, vD);
            float pdot = 0.f;
            {
                float kf[8];
                fp8x4_to_f32((unsigned int)kA.x, kf);
                fp8x4_to_f32((unsigned int)kA.y, kf + 4);
                #pragma unroll
                for (int j = 0; j < 8; ++j) pdot = fmaf(kf[j], qf[j], pdot);
            }
            pdot += __shfl_xor(pdot, 1, 64);          // combine dim-halves
            float ev = (g * 4 + es < d) ? fast_exp2(pdot) : 0.f;
            den += half ? 0.f : ev;                   // count each edge once
            {
                float vf[8];
                fp8x4_to_f32((unsigned int)vA.x, vf);
                fp8x4_to_f32((unsigned int)vA.y, vf + 4);
                #pragma unroll
                for (int j = 0; j < 8; ++j) acc[j] = fmaf(vf[j], ev, acc[j]);
            }
            kA = kB; vA = vB;
            kB = kC; vB = vC;
            kC = kD; vC = vD;
        }
    }
    den += __shfl_xor(den, 1, 64);                    // across halves
    #pragma unroll
    for (int m = 16; m < 64; m <<= 1) {               // across edge-slots
        den += __shfl_xor(den, m, 64);
        #pragma unroll
        for (int j = 0; j < 8; ++j) acc[j] += __shfl_xor(acc[j], m, 64);
    }
    if (es == 0) {
        float w = 1.f / (den + 1e-16f);
        u16x8 o;
        #pragma unroll
        for (int j = 0; j < 8; ++j) o[j] = f2bf(acc[j] * w);
        *(u16x8*)(aggb + (size_t)n * 128 + qoff) = o;
    }
}

extern "C" void kernel_launch(void* const* d_in, const int* in_sizes, int n_in,
                              void* d_out, int out_size, void* d_ws, size_t ws_size,
                              hipStream_t stream) {
    const float* x     = (const float*)d_in[0];
    const int*   eidx  = (const int*)d_in[1];
    const float* Wk    = (const float*)d_in[2];
    const float* bk    = (const float*)d_in[3];
    const float* Wq    = (const float*)d_in[4];
    const float* bq    = (const float*)d_in[5];
    const float* Wv    = (const float*)d_in[6];
    const float* bv    = (const float*)d_in[7];
    const float* a_rel = (const float*)d_in[8];
    const float* m_rel = (const float*)d_in[9];
    const float* p_rel = (const float*)d_in[10];
    const float* skip  = (const float*)d_in[11];
    const float* aW    = (const float*)d_in[12];
    const float* ab    = (const float*)d_in[13];
    const float* fcW   = (const float*)d_in[14];
    const float* fcb   = (const float*)d_in[15];
    float* out = (float*)d_out;

    float* biasf = (float*)d_ws;                              // 2*384
    unsigned short* hb   = (unsigned short*)(biasf + 768);    // NN*128 bf16
    unsigned short* qb   = hb + (size_t)NN * 128;             // NN*128 f16
    unsigned char*  kvb  = (unsigned char*)(qb + (size_t)NN * 128); // NN*256 B fp8
    unsigned short* aggb = (unsigned short*)(kvb + (size_t)NN * 256); // NN*128 bf16
    unsigned short* BfT  = aggb + (size_t)NN * 128;           // 2*384*128
    unsigned short* aWT  = BfT + 2 * 384 * 128;               // 2*128*128
    unsigned short* fcWT = aWT + 2 * 128 * 128;               // 64*128
    int* podeg     = (int*)(fcWT + 64 * 128);                 // NN (offs | deg<<20)
    int* gcur      = podeg + NN;                              // NCO (pad 160)
    int* ebuk      = gcur + 160;                              // NCO*BCAP
    int* srcSorted = ebuk + NCO * BCAP;                       // NCO*BCAP

    // zero the coarse-bucket cursors (captured as a graph memset node)
    hipMemsetAsync(gcur, 0, NCO * sizeof(int), stream);

    // weights + coarse scatter (one dispatch, disjoint block ranges)
    prep_kernel<<<P1B + WBLOCKS, 256, 0, stream>>>(
        Wq, bq, Wk, bk, a_rel, Wv, bv, m_rel, p_rel, aW, fcW,
        BfT, biasf, aWT, fcWT, eidx, gcur, ebuk);

    // layer-0 QKV GEMM + CSR pass 3 (co-scheduled)
    qkv0_p3_kernel<<<GBLOCKS + NCO, 256, 0, stream>>>(
        x, BfT, biasf, qb, kvb, gcur, ebuk, podeg, srcSorted);

    aggregate_kernel<<<NN / 4, 256, 0, stream>>>(qb, kvb, podeg, srcSorted, aggb);

    // out-GEMM(L0) -> h0 -> QKV(L1) (qb/kvb overwritten in place; agg L0 done)
    fused_kernel<0, 0><<<GBLOCKS, 256, 0, stream>>>(
        aggb, aWT, ab, skip, x, nullptr, hb,
        BfT + 49152, biasf + 384, qb, kvb, nullptr);

    aggregate_kernel<<<NN / 4, 256, 0, stream>>>(qb, kvb, podeg, srcSorted, aggb);

    // out-GEMM(L1) -> h1 (LDS) -> fc -> out
    fused_kernel<1, 2><<<GBLOCKS, 256, 0, stream>>>(
        aggb, aWT + 16384, ab + 128, skip + 1, nullptr, hb, nullptr,
        fcWT, fcb, nullptr, nullptr, out);
}